// Round 10
// baseline (266.205 us; speedup 1.0000x reference)
//
#include <hip/hip_runtime.h>
#include <hip/hip_bf16.h>
#include <cstddef>
#include <cstdint>

// Problem constants
#define NN 10000
#define EE 160000
#define ETOT (EE + NN)
#define F_IN 128
#define H1 10
#define C1 128
#define HC1 1280
#define H2 1
#define C2 1024
#define HC2 1024
#define OUT_DIM 1024

typedef __attribute__((ext_vector_type(4))) float f32x4;
typedef __attribute__((ext_vector_type(8))) short s16x8;
typedef unsigned int u32;
typedef unsigned short u16;

__device__ __forceinline__ float bf2f(u16 v) {
    union { u32 u; float f; } x; x.u = ((u32)v) << 16; return x.f;
}
__device__ __forceinline__ float bflo(u32 q) {   // low bf16 of a packed u32
    union { u32 u; float f; } x; x.u = q << 16; return x.f;
}
__device__ __forceinline__ float bfhi(u32 q) {   // high bf16 of a packed u32
    union { u32 u; float f; } x; x.u = q & 0xffff0000u; return x.f;
}
__device__ __forceinline__ u16 f2bf(float f) {
    union { float f; u32 u; } x; x.f = f;
    u32 u = x.u;
    u32 r = (u + 0x7fffu + ((u >> 16) & 1u)) >> 16;   // RNE
    return (u16)r;
}

__device__ __forceinline__ void gld16(const void* g, void* l) {
    __builtin_amdgcn_global_load_lds((const __attribute__((address_space(1))) u32*)g,
                                     (__attribute__((address_space(3))) u32*)l, 16, 0, 0);
}

// Producer-side drain of async global_load_lds BEFORE the barrier (round-6 race fix).
__device__ __forceinline__ void vm_drain() {
    asm volatile("s_waitcnt vmcnt(0)" ::: "memory");
}

// ---------------- conversions ----------------
__global__ void f32_to_bf16_kernel(const float* __restrict__ in, u16* __restrict__ out, int n) {
    int i = blockIdx.x * 256 + threadIdx.x;
    if (i < n) out[i] = f2bf(in[i]);
}

// in: [K][N] row-major f32; out: [N][K] bf16.
__global__ void transpose_bf16_kernel(const float* __restrict__ in, u16* __restrict__ out,
                                      int K, int N) {
    __shared__ u16 t[16][17];
    int n0 = blockIdx.x * 16, k0 = blockIdx.y * 16;
    t[threadIdx.y][threadIdx.x] = f2bf(in[(size_t)(k0 + threadIdx.y) * N + n0 + threadIdx.x]);
    __syncthreads();
    out[(size_t)(n0 + threadIdx.y) * K + k0 + threadIdx.x] = t[threadIdx.x][threadIdx.y];
}

// ---------------- CSR build ----------------
__global__ void hist_kernel(const int* __restrict__ edst, int* __restrict__ deg) {
    int e = blockIdx.x * 256 + threadIdx.x;
    if (e >= ETOT) return;
    int d = (e < EE) ? edst[e] : (e - EE);
    atomicAdd(&deg[d], 1);
}

// shfl-based single-block scan (1024 threads)
__global__ void scan_kernel(const int* __restrict__ deg, int* __restrict__ row_start) {
    __shared__ int wsum[16];
    const int tid = threadIdx.x;
    const int lane = tid & 63;
    const int wid = tid >> 6;
    int carry = 0;
    for (int base = 0; base < NN; base += 1024) {
        int i = base + tid;
        int v = (i < NN) ? deg[i] : 0;
        int x = v;
#pragma unroll
        for (int o = 1; o < 64; o <<= 1) {
            int t = __shfl_up(x, o);
            if (lane >= o) x += t;
        }
        if (lane == 63) wsum[wid] = x;
        __syncthreads();
        if (wid == 0) {
            int w = (lane < 16) ? wsum[lane] : 0;
#pragma unroll
            for (int o = 1; o < 16; o <<= 1) {
                int t = __shfl_up(w, o);
                if (lane >= o) w += t;
            }
            if (lane < 16) wsum[lane] = w;
        }
        __syncthreads();
        int woff = (wid == 0) ? 0 : wsum[wid - 1];
        if (i < NN) row_start[i] = carry + woff + x - v;   // exclusive
        carry += wsum[15];
        __syncthreads();
    }
    if (tid == 0) row_start[NN] = carry;
}

__global__ void fill_kernel(const int* __restrict__ esrc, const int* __restrict__ edst,
                            const int* __restrict__ row_start, int* __restrict__ cursor,
                            int* __restrict__ slot_src) {
    int e = blockIdx.x * 256 + threadIdx.x;
    if (e >= ETOT) return;
    int s, d;
    if (e < EE) { s = esrc[e]; d = edst[e]; }
    else        { s = d = e - EE; }
    int pos = atomicAdd(&cursor[d], 1);
    slot_src[row_start[d] + pos] = s;
}

// ---------------- bf16 MFMA GEMM: C = A[MxK] * Bt[NxK]^T ----------------
// 128x128 tile, 4 waves (2x2), 16x16x32 MFMA, BK=64: 32 MFMAs per drain+barrier
// (R9 showed the per-iteration drain is the cost; BK=64 halves its frequency).
// T2 XOR bank-swizzle: global_load_lds writes LDS linearly, so the SOURCE column
// is pre-swizzled (block b at row r loads global block b^(r&7)) and the ds_read
// applies the same XOR — spreads each fragment read over all 8 bank groups.
// Double-buffered + explicit producer vmcnt drain (round-6 race fix) + bijective
// XCD swizzle. BIAS_RELU==1: +bias, relu, f32 out. HEADMAJ==1: bf16 head-major
// planes [n/128][M][128].
template<int BIAS_RELU, int HEADMAJ>
__global__ __launch_bounds__(256, 2)
void gemm_bf16(const u16* __restrict__ A, const u16* __restrict__ Bt,
               const float* __restrict__ bias, void* __restrict__ Cout,
               int M, int N, int K) {
    __shared__ u16 Als[2][128 * 64];
    __shared__ u16 Bls[2][128 * 64];
    const int tid  = threadIdx.x;
    const int wave = tid >> 6;
    const int lane = tid & 63;

    // bijective XCD swizzle
    const int nwg = gridDim.x * gridDim.y;
    const int bid = blockIdx.y * gridDim.x + blockIdx.x;
    const int q = nwg >> 3, r = nwg & 7;
    const int xcd = bid & 7, idx = bid >> 3;
    const int swz = (xcd < r ? xcd * (q + 1) : r * (q + 1) + (xcd - r) * q) + idx;
    const int bm = (swz / gridDim.x) * 128;
    const int bn = (swz % gridDim.x) * 128;

    const int wr = wave >> 1, wc = wave & 1;   // 2x2 waves, each 64x64
    const int lr = lane & 15;
    const int kc = lane >> 4;

    f32x4 acc[4][4] = {};

    // staging geometry: tile = 4 chunks x (32 rows x 64 cols); thread t covers
    // chunk-row t>>3, 16B-block t&7, with XOR-swizzled SOURCE column.
    const int srow = tid >> 3;                       // 0..31
    const int sblk = tid & 7;                        // 16B block in 128B row
    const int scol = 8 * (sblk ^ (srow & 7));        // swizzled element col
    const u16 *aP[4], *bP[4];
#pragma unroll
    for (int c = 0; c < 4; ++c) {
        int ra = bm + c * 32 + srow; if (ra >= M) ra = M - 1;   // pad rows never stored
        aP[c] = A  + (size_t)ra * K + scol;
        bP[c] = Bt + (size_t)(bn + c * 32 + srow) * K + scol;   // N multiple of 128
    }

    // prologue: stage tile 0 into buf 0
#pragma unroll
    for (int c = 0; c < 4; ++c) {
        gld16(aP[c], &Als[0][c * 2048 + wave * 512]);
        gld16(bP[c], &Bls[0][c * 2048 + wave * 512]);
    }
    vm_drain();
    __syncthreads();

    int cur = 0;
    for (int k0 = 0; k0 < K; k0 += 64) {
        if (k0 + 64 < K) {
            int nxt = cur ^ 1;
#pragma unroll
            for (int c = 0; c < 4; ++c) {
                gld16(aP[c] + k0 + 64, &Als[nxt][c * 2048 + wave * 512]);
                gld16(bP[c] + k0 + 64, &Bls[nxt][c * 2048 + wave * 512]);
            }
        }

#pragma unroll
        for (int kh = 0; kh < 2; ++kh) {
            // global k-block (kc+4*kh) lives at LDS block (kc+4*kh)^(row&7);
            // row&7 == lr&7 for all fragment rows (row = base + lr, base%8==0).
            const int sb = ((kc + 4 * kh) ^ (lr & 7)) * 8;
            s16x8 af[4], bg[4];
#pragma unroll
            for (int i = 0; i < 4; ++i)
                af[i] = *(const s16x8*)&Als[cur][(wr * 64 + i * 16 + lr) * 64 + sb];
#pragma unroll
            for (int j = 0; j < 4; ++j)
                bg[j] = *(const s16x8*)&Bls[cur][(wc * 64 + j * 16 + lr) * 64 + sb];
#pragma unroll
            for (int i = 0; i < 4; ++i)
#pragma unroll
                for (int j = 0; j < 4; ++j)
                    acc[i][j] = __builtin_amdgcn_mfma_f32_16x16x32_bf16(af[i], bg[j], acc[i][j], 0, 0, 0);
        }

        vm_drain();      // prefetch visible to ALL waves before the barrier
        __syncthreads();
        cur ^= 1;
    }

    // C/D layout: col = lane&15, row = (lane>>4)*4 + reg
#pragma unroll
    for (int i = 0; i < 4; ++i) {
#pragma unroll
        for (int r2 = 0; r2 < 4; ++r2) {
            int m = bm + wr * 64 + i * 16 + kc * 4 + r2;
            if (m >= M) continue;
#pragma unroll
            for (int j = 0; j < 4; ++j) {
                int n = bn + wc * 64 + j * 16 + lr;
                float v = acc[i][j][r2];
                if (BIAS_RELU) {
                    v += bias[n];
                    v = fmaxf(v, 0.f);
                    ((float*)Cout)[(size_t)m * N + n] = v;
                } else if (HEADMAJ) {
                    ((u16*)Cout)[(size_t)(n >> 7) * NN * 128 + (size_t)m * 128 + (n & 127)] = f2bf(v);
                } else {
                    ((u16*)Cout)[(size_t)m * N + n] = f2bf(v);
                }
            }
        }
    }
}

// ---------------- logits: 4 ch/lane vector loads ----------------
// PLANAR: h stored as [head][NN][C] planes. H even: half-wave per head pair member.
template<int H, int C, bool PLANAR>
__global__ __launch_bounds__(128)
void att_logits3(const u16* __restrict__ h, const float* __restrict__ att_s,
                 const float* __restrict__ att_d, float* __restrict__ a_s,
                 float* __restrict__ a_d) {
    const int n = blockIdx.x * 2 + (threadIdx.x >> 6);
    const int lane = threadIdx.x & 63;
    if constexpr (H == 1) {
        const u16* row = h + (size_t)n * C;
        float ps = 0.f, pd = 0.f;
        for (int c = lane * 4; c < C; c += 256) {
            uint2 q = *(const uint2*)(row + c);
            float4 s = *(const float4*)(att_s + c);
            float4 dd = *(const float4*)(att_d + c);
            float v0 = bflo(q.x), v1 = bfhi(q.x), v2 = bflo(q.y), v3 = bfhi(q.y);
            ps += v0 * s.x + v1 * s.y + v2 * s.z + v3 * s.w;
            pd += v0 * dd.x + v1 * dd.y + v2 * dd.z + v3 * dd.w;
        }
#pragma unroll
        for (int off = 32; off; off >>= 1) {
            ps += __shfl_down(ps, off);
            pd += __shfl_down(pd, off);
        }
        if (lane == 0) { a_s[n] = ps; a_d[n] = pd; }
    } else {
        const int sub = lane >> 5;        // which head of the pair
        const int lg  = lane & 31;        // 32 lanes x 4ch = 128 = C
#pragma unroll
        for (int hp = 0; hp < H / 2; ++hp) {
            const int hd = hp * 2 + sub;
            const int c = lg * 4;
            const u16* rp = PLANAR ? (h + ((size_t)hd * NN + n) * C + c)
                                   : (h + (size_t)n * H * C + hd * C + c);
            uint2 q = *(const uint2*)rp;
            float4 s = *(const float4*)(att_s + hd * C + c);
            float4 dd = *(const float4*)(att_d + hd * C + c);
            float v0 = bflo(q.x), v1 = bfhi(q.x), v2 = bflo(q.y), v3 = bfhi(q.y);
            float ps = v0 * s.x + v1 * s.y + v2 * s.z + v3 * s.w;
            float pd = v0 * dd.x + v1 * dd.y + v2 * dd.z + v3 * dd.w;
#pragma unroll
            for (int off = 16; off; off >>= 1) {
                ps += __shfl_down(ps, off, 32);
                pd += __shfl_down(pd, off, 32);
            }
            if (lg == 0) {
                a_s[n * H + hd] = ps;
                a_d[n * H + hd] = pd;
            }
        }
    }
}

// ---------------- alpha: unnormalized exp (TRANSPOSED planes [H][ETOT]) + inv sums ----
template<int H>
__global__ __launch_bounds__(128)
void att_alpha3(const int* __restrict__ row_start, const int* __restrict__ slot_src,
                const float* __restrict__ a_s, const float* __restrict__ a_d,
                float* __restrict__ exal_t, float* __restrict__ inv) {
    const int d = blockIdx.x * 2 + (threadIdx.x >> 6);
    const int lane = threadIdx.x & 63;
    const int s0 = row_start[d], s1 = row_start[d + 1];
    float ad[H];
#pragma unroll
    for (int hd = 0; hd < H; ++hd) ad[hd] = a_d[(size_t)d * H + hd];
    float sums[H];
#pragma unroll
    for (int hd = 0; hd < H; ++hd) sums[hd] = 0.f;

    for (int base = s0; base < s1; base += 64) {
        int e = base + lane;
        bool ok = (e < s1);
        int src = ok ? slot_src[e] : 0;
        float as[H];
        if constexpr (H == 1) {
            as[0] = ok ? a_s[src] : 0.f;
        } else {
            const float2* asp = (const float2*)(a_s + (size_t)src * H);
#pragma unroll
            for (int i = 0; i < H / 2; ++i) {
                float2 q = ok ? asp[i] : make_float2(0.f, 0.f);
                as[2 * i] = q.x; as[2 * i + 1] = q.y;
            }
        }
#pragma unroll
        for (int hd = 0; hd < H; ++hd) {
            float t = as[hd] + ad[hd];
            t = (t > 0.f) ? t : 0.2f * t;          // leaky_relu 0.2
            float x = ok ? expf(t) : 0.f;          // logits small by construction
            sums[hd] += x;
            if (ok) exal_t[(size_t)hd * ETOT + e] = x;   // coalesced per plane
        }
    }
#pragma unroll
    for (int hd = 0; hd < H; ++hd) {
#pragma unroll
        for (int off = 32; off; off >>= 1) sums[hd] += __shfl_down(sums[hd], off);
    }
    if (lane == 0) {
#pragma unroll
        for (int hd = 0; hd < H; ++hd) inv[(size_t)d * H + hd] = 1.f / (sums[hd] + 1e-16f);
    }
}

// helper: accumulate 8 channels from a uint4 of packed bf16
__device__ __forceinline__ void fma8(float* acc, uint4 g, float a) {
    acc[0] += a * bflo(g.x); acc[1] += a * bfhi(g.x);
    acc[2] += a * bflo(g.y); acc[3] += a * bfhi(g.y);
    acc[4] += a * bflo(g.z); acc[5] += a * bfhi(g.z);
    acc[6] += a * bflo(g.w); acc[7] += a * bfhi(g.w);
}

// ---------------- scatter v5: L2-resident phases ----------------
// 16-lane groups, 8 ch/lane (16B gathers, 256B contiguous per group per edge).
// PLANAR (layer 1): h = [head][NN][128] planes, blockIdx.y = head.
// !PLANAR (layer 2): h = [NN][HC] node-major, blockIdx.y = 128-ch column slice.
// ACT: 1 = elu, 2 = relu.
template<int ACT, int H, int HC, bool PLANAR>
__global__ __launch_bounds__(128)
void gat_scatter5(const int* __restrict__ row_start, const int* __restrict__ slot_src,
                  const float* __restrict__ exal_t, const float* __restrict__ inv,
                  const u16* __restrict__ h, const float* __restrict__ bias,
                  u16* __restrict__ out) {
    const int grp = threadIdx.x >> 4;          // 0..7
    const int lg  = threadIdx.x & 15;
    const int d   = blockIdx.x * 8 + grp;
    const int y   = blockIdx.y;                // head (l1) or channel slice (l2)
    const int cc  = y * 128 + lg * 8;          // output channel base
    const int s0 = row_start[d], s1 = row_start[d + 1];
    const float* exp_pl = exal_t + (size_t)(PLANAR ? y : 0) * ETOT;
    const u16* hb = PLANAR ? (h + (size_t)y * NN * 128 + lg * 8)
                           : (h + cc);
    const int hstride = PLANAR ? 128 : HC;

    float acc0[8] = {}, acc1[8] = {}, acc2[8] = {}, acc3[8] = {};

    for (int base = s0; base < s1; base += 16) {
        int e = base + lg;
        bool ok = (e < s1);
        int mySrc = 0; float mA = 0.f;
        if (ok) { mySrc = slot_src[e]; mA = exp_pl[e]; }
        int cnt = min(16, s1 - base);
        int j = 0;
        for (; j + 4 <= cnt; j += 4) {
            int sA = __shfl(mySrc, j, 16),     sB = __shfl(mySrc, j + 1, 16);
            int sC = __shfl(mySrc, j + 2, 16), sD = __shfl(mySrc, j + 3, 16);
            float aA = __shfl(mA, j, 16),     aB = __shfl(mA, j + 1, 16);
            float aC = __shfl(mA, j + 2, 16), aD = __shfl(mA, j + 3, 16);
            uint4 gA = *(const uint4*)(hb + (size_t)sA * hstride);
            uint4 gB = *(const uint4*)(hb + (size_t)sB * hstride);
            uint4 gC = *(const uint4*)(hb + (size_t)sC * hstride);
            uint4 gD = *(const uint4*)(hb + (size_t)sD * hstride);
            fma8(acc0, gA, aA); fma8(acc1, gB, aB);
            fma8(acc2, gC, aC); fma8(acc3, gD, aD);
        }
        for (; j < cnt; ++j) {
            int sA = __shfl(mySrc, j, 16);
            float aA = __shfl(mA, j, 16);
            uint4 gA = *(const uint4*)(hb + (size_t)sA * hstride);
            fma8(acc0, gA, aA);
        }
    }

    float sc = inv[(size_t)d * H + (PLANAR ? y : 0)];
    float4 b0 = *(const float4*)(bias + cc);
    float4 b1 = *(const float4*)(bias + cc + 4);
    float bb[8] = { b0.x, b0.y, b0.z, b0.w, b1.x, b1.y, b1.z, b1.w };
    u16 os[8];
#pragma unroll
    for (int k = 0; k < 8; ++k) {
        float v = (acc0[k] + acc1[k]) + (acc2[k] + acc3[k]);
        v = v * sc + bb[k];
        if (ACT == 1) v = (v > 0.f) ? v : (expf(v) - 1.f);   // elu
        else          v = fmaxf(v, 0.f);                      // relu
        os[k] = f2bf(v);
    }
    uint4 q;
    q.x = (u32)os[0] | ((u32)os[1] << 16);
    q.y = (u32)os[2] | ((u32)os[3] << 16);
    q.z = (u32)os[4] | ((u32)os[5] << 16);
    q.w = (u32)os[6] | ((u32)os[7] << 16);
    *(uint4*)(out + (size_t)d * HC + cc) = q;
}

extern "C" void kernel_launch(void* const* d_in, const int* in_sizes, int n_in,
                              void* d_out, int out_size, void* d_ws, size_t ws_size,
                              hipStream_t stream) {
    const float* node      = (const float*)d_in[0];
    const int*   esrc      = (const int*)d_in[1];          // edge_index[0]
    const int*   edst      = ((const int*)d_in[1]) + EE;   // edge_index[1]
    const float* W1        = (const float*)d_in[2];
    const float* att_src1  = (const float*)d_in[3];
    const float* att_dst1  = (const float*)d_in[4];
    const float* b1        = (const float*)d_in[5];
    const float* W2        = (const float*)d_in[6];
    const float* att_src2  = (const float*)d_in[7];
    const float* att_dst2  = (const float*)d_in[8];
    const float* b2        = (const float*)d_in[9];
    const float* fc_w      = (const float*)d_in[10];
    const float* fc_b      = (const float*)d_in[11];
    float* out = (float*)d_out;

    // ---- workspace layout ----
    u16* bufA  = (u16*)d_ws;                        // [NN*HC1]  h1 planes, later h2
    u16* bufB  = bufA + (size_t)NN * HC1;           // [NN*HC1]  x2b, later out2b
    u16* nodeb = bufB + (size_t)NN * HC1;           // [NN*F_IN]
    u16* w1t   = nodeb + (size_t)NN * F_IN;         // [HC1*F_IN]
    u16* w2t   = w1t + (size_t)HC1 * F_IN;          // [HC2*HC1]
    u16* fcwt  = w2t + (size_t)HC2 * HC1;           // [OUT_DIM*OUT_DIM]
    float* exal  = (float*)(fcwt + (size_t)OUT_DIM * OUT_DIM);  // [H1*ETOT] planes
    float* inv   = exal + (size_t)ETOT * H1;        // [NN*H1]
    float* a_s1  = inv + (size_t)NN * H1;           // [NN*H1]
    float* a_d1  = a_s1 + (size_t)NN * H1;
    float* a_s2  = a_d1 + (size_t)NN * H1;          // [NN]
    float* a_d2  = a_s2 + NN;
    int* deg       = (int*)(a_d2 + NN);
    int* cursor    = deg + NN;
    int* row_start = cursor + NN;                   // [NN+1]
    int* slot_src  = row_start + NN + 8;            // [ETOT]

    // ---- conversions ----
    f32_to_bf16_kernel<<<(NN * F_IN + 255) / 256, 256, 0, stream>>>(node, nodeb, NN * F_IN);
    transpose_bf16_kernel<<<dim3(HC1 / 16, F_IN / 16), dim3(16, 16), 0, stream>>>(W1, w1t, F_IN, HC1);
    transpose_bf16_kernel<<<dim3(HC2 / 16, HC1 / 16), dim3(16, 16), 0, stream>>>(W2, w2t, HC1, HC2);
    transpose_bf16_kernel<<<dim3(OUT_DIM / 16, OUT_DIM / 16), dim3(16, 16), 0, stream>>>(fc_w, fcwt, OUT_DIM, OUT_DIM);

    // ---- CSR build ----
    hipMemsetAsync(deg, 0, 2 * NN * sizeof(int), stream);  // deg + cursor
    hist_kernel<<<(ETOT + 255) / 256, 256, 0, stream>>>(edst, deg);
    scan_kernel<<<1, 1024, 0, stream>>>(deg, row_start);
    fill_kernel<<<(ETOT + 255) / 256, 256, 0, stream>>>(esrc, edst, row_start, cursor, slot_src);

    // ---- layer 1 (h1 stored as head-major planes) ----
    gemm_bf16<0, 1><<<dim3(HC1 / 128, (NN + 127) / 128), 256, 0, stream>>>(nodeb, w1t, nullptr, bufA, NN, HC1, F_IN);
    att_logits3<H1, C1, true><<<NN / 2, 128, 0, stream>>>(bufA, att_src1, att_dst1, a_s1, a_d1);
    att_alpha3<H1><<<NN / 2, 128, 0, stream>>>(row_start, slot_src, a_s1, a_d1, exal, inv);
    gat_scatter5<1, H1, HC1, true><<<dim3(NN / 8, H1), 128, 0, stream>>>(row_start, slot_src, exal, inv, bufA, b1, bufB);

    // ---- layer 2 (node-major, channel-slice phases) ----
    gemm_bf16<0, 0><<<dim3(HC2 / 128, (NN + 127) / 128), 256, 0, stream>>>(bufB, w2t, nullptr, bufA, NN, HC2, HC1);
    att_logits3<H2, C2, false><<<NN / 2, 128, 0, stream>>>(bufA, att_src2, att_dst2, a_s2, a_d2);
    att_alpha3<H2><<<NN / 2, 128, 0, stream>>>(row_start, slot_src, a_s2, a_d2, exal, inv);
    gat_scatter5<2, H2, HC2, false><<<dim3(NN / 8, HC2 / 128), 128, 0, stream>>>(row_start, slot_src, exal, inv, bufA, b2, bufB);

    // ---- fc: out = relu(out2 @ fc_w + fc_b), f32 out ----
    gemm_bf16<1, 0><<<dim3(OUT_DIM / 128, (NN + 127) / 128), 256, 0, stream>>>(bufB, fcwt, fc_b, out, NN, OUT_DIM, OUT_DIM);
}

// Round 11
// 262.474 us; speedup vs baseline: 1.0142x; 1.0142x over previous
//
#include <hip/hip_runtime.h>
#include <hip/hip_bf16.h>
#include <cstddef>
#include <cstdint>

// Problem constants
#define NN 10000
#define EE 160000
#define ETOT (EE + NN)
#define F_IN 128
#define H1 10
#define C1 128
#define HC1 1280
#define H2 1
#define C2 1024
#define HC2 1024
#define OUT_DIM 1024

typedef __attribute__((ext_vector_type(4))) float f32x4;
typedef __attribute__((ext_vector_type(8))) short s16x8;
typedef unsigned int u32;
typedef unsigned short u16;

__device__ __forceinline__ float bf2f(u16 v) {
    union { u32 u; float f; } x; x.u = ((u32)v) << 16; return x.f;
}
__device__ __forceinline__ float bflo(u32 q) {   // low bf16 of a packed u32
    union { u32 u; float f; } x; x.u = q << 16; return x.f;
}
__device__ __forceinline__ float bfhi(u32 q) {   // high bf16 of a packed u32
    union { u32 u; float f; } x; x.u = q & 0xffff0000u; return x.f;
}
__device__ __forceinline__ u16 f2bf(float f) {
    union { float f; u32 u; } x; x.f = f;
    u32 u = x.u;
    u32 r = (u + 0x7fffu + ((u >> 16) & 1u)) >> 16;   // RNE
    return (u16)r;
}

__device__ __forceinline__ void gld16(const void* g, void* l) {
    __builtin_amdgcn_global_load_lds((const __attribute__((address_space(1))) u32*)g,
                                     (__attribute__((address_space(3))) u32*)l, 16, 0, 0);
}

// ---------------- conversions ----------------
__global__ void f32_to_bf16_kernel(const float* __restrict__ in, u16* __restrict__ out, int n) {
    int i = blockIdx.x * 256 + threadIdx.x;
    if (i < n) out[i] = f2bf(in[i]);
}

// in: [K][N] row-major f32; out: [N][K] bf16.
__global__ void transpose_bf16_kernel(const float* __restrict__ in, u16* __restrict__ out,
                                      int K, int N) {
    __shared__ u16 t[16][17];
    int n0 = blockIdx.x * 16, k0 = blockIdx.y * 16;
    t[threadIdx.y][threadIdx.x] = f2bf(in[(size_t)(k0 + threadIdx.y) * N + n0 + threadIdx.x]);
    __syncthreads();
    out[(size_t)(n0 + threadIdx.y) * K + k0 + threadIdx.x] = t[threadIdx.x][threadIdx.y];
}

// ---------------- CSR build ----------------
__global__ void hist_kernel(const int* __restrict__ edst, int* __restrict__ deg) {
    int e = blockIdx.x * 256 + threadIdx.x;
    if (e >= ETOT) return;
    int d = (e < EE) ? edst[e] : (e - EE);
    atomicAdd(&deg[d], 1);
}

// shfl-based single-block scan (1024 threads)
__global__ void scan_kernel(const int* __restrict__ deg, int* __restrict__ row_start) {
    __shared__ int wsum[16];
    const int tid = threadIdx.x;
    const int lane = tid & 63;
    const int wid = tid >> 6;
    int carry = 0;
    for (int base = 0; base < NN; base += 1024) {
        int i = base + tid;
        int v = (i < NN) ? deg[i] : 0;
        int x = v;
#pragma unroll
        for (int o = 1; o < 64; o <<= 1) {
            int t = __shfl_up(x, o);
            if (lane >= o) x += t;
        }
        if (lane == 63) wsum[wid] = x;
        __syncthreads();
        if (wid == 0) {
            int w = (lane < 16) ? wsum[lane] : 0;
#pragma unroll
            for (int o = 1; o < 16; o <<= 1) {
                int t = __shfl_up(w, o);
                if (lane >= o) w += t;
            }
            if (lane < 16) wsum[lane] = w;
        }
        __syncthreads();
        int woff = (wid == 0) ? 0 : wsum[wid - 1];
        if (i < NN) row_start[i] = carry + woff + x - v;   // exclusive
        carry += wsum[15];
        __syncthreads();
    }
    if (tid == 0) row_start[NN] = carry;
}

__global__ void fill_kernel(const int* __restrict__ esrc, const int* __restrict__ edst,
                            const int* __restrict__ row_start, int* __restrict__ cursor,
                            int* __restrict__ slot_src) {
    int e = blockIdx.x * 256 + threadIdx.x;
    if (e >= ETOT) return;
    int s, d;
    if (e < EE) { s = esrc[e]; d = edst[e]; }
    else        { s = d = e - EE; }
    int pos = atomicAdd(&cursor[d], 1);
    slot_src[row_start[d] + pos] = s;
}

// ---------------- bf16 MFMA GEMM: C = A[MxK] * Bt[NxK]^T ----------------
// 128x128 tile, 2 waves (each 64Mx128N: 4x8 frags = 32 MFMA / 12 ds_read per
// step -> balanced LDS:MFMA), BK=32, 3 LDS buffers with COUNTED vmcnt pipeline:
// tile t+2's loads are issued at step t and stay in flight across the barrier
// (wait vmcnt(8) drains only t+1) -> ~2 steps (>600cy) of latency cover.
// Raw s_barrier, each immediately preceded by a memory-clobber s_waitcnt
// (race-safe: a buffer is rewritten only 2 steps after its last read).
// XOR bank swizzle on 16B blocks (b ^ ((row>>1)&3)) via pre-swizzled global
// source (global_load_lds writes linearly) + same XOR on ds_read.
// Bijective XCD swizzle. BIAS_RELU==1: +bias, relu, f32 out.
// HEADMAJ==1: bf16 head-major planes [n/128][M][128].
template<int BIAS_RELU, int HEADMAJ>
__global__ __launch_bounds__(128, 2)
void gemm_bf16(const u16* __restrict__ A, const u16* __restrict__ Bt,
               const float* __restrict__ bias, void* __restrict__ Cout,
               int M, int N, int K) {
    __shared__ u16 Als[3][128 * 32];
    __shared__ u16 Bls[3][128 * 32];
    const int tid  = threadIdx.x;        // 0..127 (2 waves)
    const int wave = tid >> 6;           // 0..1
    const int lane = tid & 63;

    // bijective XCD swizzle
    const int nwg = gridDim.x * gridDim.y;
    const int bid = blockIdx.y * gridDim.x + blockIdx.x;
    const int q = nwg >> 3, r = nwg & 7;
    const int xcd = bid & 7, idx = bid >> 3;
    const int swz = (xcd < r ? xcd * (q + 1) : r * (q + 1) + (xcd - r) * q) + idx;
    const int bm = (swz / gridDim.x) * 128;
    const int bn = (swz % gridDim.x) * 128;

    const int lr = lane & 15;
    const int kc = lane >> 4;

    f32x4 acc[4][8] = {};

    // staging: thread t covers row (t>>2) of each 32-row chunk, 16B block t&3.
    // Source block pre-swizzled: sg = (l&3) ^ ((l>>3)&3)  (matches reader XOR).
    const int rt = tid >> 2;                         // 0..31
    const int sg = (lane & 3) ^ ((lane >> 3) & 3);
    const int scol = sg * 8;
    const u16 *aP[4], *bP[4];
#pragma unroll
    for (int c = 0; c < 4; ++c) {
        int ra = bm + c * 32 + rt; if (ra >= M) ra = M - 1;   // pad rows never stored
        aP[c] = A  + (size_t)ra * K + scol;
        bP[c] = Bt + (size_t)(bn + c * 32 + rt) * K + scol;   // N multiple of 128
    }

#define STAGE(ib, ko)                                                   \
    do {                                                                \
        _Pragma("unroll")                                               \
        for (int c = 0; c < 4; ++c) {                                   \
            gld16(aP[c] + (ko), &Als[ib][c * 1024 + wave * 512]);       \
            gld16(bP[c] + (ko), &Bls[ib][c * 1024 + wave * 512]);       \
        }                                                               \
    } while (0)

    const int NT = K >> 5;               // K/32 (K in {128,1024,1280})

    // prologue: tiles 0 and 1 in flight; wait for tile 0 only.
    STAGE(0, 0);
    if (NT > 1) {
        STAGE(1, 32);
        asm volatile("s_waitcnt vmcnt(8)" ::: "memory");
    } else {
        asm volatile("s_waitcnt vmcnt(0)" ::: "memory");
    }
    __builtin_amdgcn_s_barrier();

    int cur = 0, nxt2 = 2;
    for (int t = 0; t < NT; ++t) {
        if (t + 2 < NT) STAGE(nxt2, (t + 2) * 32);

        const int sb = (kc ^ ((lr >> 1) & 3)) * 8;   // un-swizzle on read
        s16x8 af[4], bg[8];
#pragma unroll
        for (int i = 0; i < 4; ++i)
            af[i] = *(const s16x8*)&Als[cur][(wave * 64 + i * 16 + lr) * 32 + sb];
#pragma unroll
        for (int j = 0; j < 8; ++j)
            bg[j] = *(const s16x8*)&Bls[cur][(j * 16 + lr) * 32 + sb];
#pragma unroll
        for (int i = 0; i < 4; ++i)
#pragma unroll
            for (int j = 0; j < 8; ++j)
                acc[i][j] = __builtin_amdgcn_mfma_f32_16x16x32_bf16(af[i], bg[j], acc[i][j], 0, 0, 0);

        if (t < NT - 1) {
            if (t + 2 < NT) asm volatile("s_waitcnt vmcnt(8)" ::: "memory");  // t+1 done, t+2 in flight
            else            asm volatile("s_waitcnt vmcnt(0)" ::: "memory");  // drain tail
            __builtin_amdgcn_s_barrier();
            cur  = (cur  == 2) ? 0 : cur  + 1;
            nxt2 = (nxt2 == 2) ? 0 : nxt2 + 1;
        }
    }
#undef STAGE

    // C/D layout: col = lane&15, row = (lane>>4)*4 + reg
#pragma unroll
    for (int i = 0; i < 4; ++i) {
#pragma unroll
        for (int r2 = 0; r2 < 4; ++r2) {
            int m = bm + wave * 64 + i * 16 + kc * 4 + r2;
            if (m >= M) continue;
#pragma unroll
            for (int j = 0; j < 8; ++j) {
                int n = bn + j * 16 + lr;
                float v = acc[i][j][r2];
                if (BIAS_RELU) {
                    v += bias[n];
                    v = fmaxf(v, 0.f);
                    ((float*)Cout)[(size_t)m * N + n] = v;
                } else if (HEADMAJ) {
                    ((u16*)Cout)[(size_t)(n >> 7) * NN * 128 + (size_t)m * 128 + (n & 127)] = f2bf(v);
                } else {
                    ((u16*)Cout)[(size_t)m * N + n] = f2bf(v);
                }
            }
        }
    }
}

// ---------------- logits: 4 ch/lane vector loads ----------------
// PLANAR: h stored as [head][NN][C] planes. H even: half-wave per head pair member.
template<int H, int C, bool PLANAR>
__global__ __launch_bounds__(128)
void att_logits3(const u16* __restrict__ h, const float* __restrict__ att_s,
                 const float* __restrict__ att_d, float* __restrict__ a_s,
                 float* __restrict__ a_d) {
    const int n = blockIdx.x * 2 + (threadIdx.x >> 6);
    const int lane = threadIdx.x & 63;
    if constexpr (H == 1) {
        const u16* row = h + (size_t)n * C;
        float ps = 0.f, pd = 0.f;
        for (int c = lane * 4; c < C; c += 256) {
            uint2 q = *(const uint2*)(row + c);
            float4 s = *(const float4*)(att_s + c);
            float4 dd = *(const float4*)(att_d + c);
            float v0 = bflo(q.x), v1 = bfhi(q.x), v2 = bflo(q.y), v3 = bfhi(q.y);
            ps += v0 * s.x + v1 * s.y + v2 * s.z + v3 * s.w;
            pd += v0 * dd.x + v1 * dd.y + v2 * dd.z + v3 * dd.w;
        }
#pragma unroll
        for (int off = 32; off; off >>= 1) {
            ps += __shfl_down(ps, off);
            pd += __shfl_down(pd, off);
        }
        if (lane == 0) { a_s[n] = ps; a_d[n] = pd; }
    } else {
        const int sub = lane >> 5;        // which head of the pair
        const int lg  = lane & 31;        // 32 lanes x 4ch = 128 = C
#pragma unroll
        for (int hp = 0; hp < H / 2; ++hp) {
            const int hd = hp * 2 + sub;
            const int c = lg * 4;
            const u16* rp = PLANAR ? (h + ((size_t)hd * NN + n) * C + c)
                                   : (h + (size_t)n * H * C + hd * C + c);
            uint2 q = *(const uint2*)rp;
            float4 s = *(const float4*)(att_s + hd * C + c);
            float4 dd = *(const float4*)(att_d + hd * C + c);
            float v0 = bflo(q.x), v1 = bfhi(q.x), v2 = bflo(q.y), v3 = bfhi(q.y);
            float ps = v0 * s.x + v1 * s.y + v2 * s.z + v3 * s.w;
            float pd = v0 * dd.x + v1 * dd.y + v2 * dd.z + v3 * dd.w;
#pragma unroll
            for (int off = 16; off; off >>= 1) {
                ps += __shfl_down(ps, off, 32);
                pd += __shfl_down(pd, off, 32);
            }
            if (lg == 0) {
                a_s[n * H + hd] = ps;
                a_d[n * H + hd] = pd;
            }
        }
    }
}

// ---------------- alpha: unnormalized exp (TRANSPOSED planes [H][ETOT]) + inv sums ----
template<int H>
__global__ __launch_bounds__(128)
void att_alpha3(const int* __restrict__ row_start, const int* __restrict__ slot_src,
                const float* __restrict__ a_s, const float* __restrict__ a_d,
                float* __restrict__ exal_t, float* __restrict__ inv) {
    const int d = blockIdx.x * 2 + (threadIdx.x >> 6);
    const int lane = threadIdx.x & 63;
    const int s0 = row_start[d], s1 = row_start[d + 1];
    float ad[H];
#pragma unroll
    for (int hd = 0; hd < H; ++hd) ad[hd] = a_d[(size_t)d * H + hd];
    float sums[H];
#pragma unroll
    for (int hd = 0; hd < H; ++hd) sums[hd] = 0.f;

    for (int base = s0; base < s1; base += 64) {
        int e = base + lane;
        bool ok = (e < s1);
        int src = ok ? slot_src[e] : 0;
        float as[H];
        if constexpr (H == 1) {
            as[0] = ok ? a_s[src] : 0.f;
        } else {
            const float2* asp = (const float2*)(a_s + (size_t)src * H);
#pragma unroll
            for (int i = 0; i < H / 2; ++i) {
                float2 q = ok ? asp[i] : make_float2(0.f, 0.f);
                as[2 * i] = q.x; as[2 * i + 1] = q.y;
            }
        }
#pragma unroll
        for (int hd = 0; hd < H; ++hd) {
            float t = as[hd] + ad[hd];
            t = (t > 0.f) ? t : 0.2f * t;          // leaky_relu 0.2
            float x = ok ? expf(t) : 0.f;          // logits small by construction
            sums[hd] += x;
            if (ok) exal_t[(size_t)hd * ETOT + e] = x;   // coalesced per plane
        }
    }
#pragma unroll
    for (int hd = 0; hd < H; ++hd) {
#pragma unroll
        for (int off = 32; off; off >>= 1) sums[hd] += __shfl_down(sums[hd], off);
    }
    if (lane == 0) {
#pragma unroll
        for (int hd = 0; hd < H; ++hd) inv[(size_t)d * H + hd] = 1.f / (sums[hd] + 1e-16f);
    }
}

// helper: accumulate 8 channels from a uint4 of packed bf16
__device__ __forceinline__ void fma8(float* acc, uint4 g, float a) {
    acc[0] += a * bflo(g.x); acc[1] += a * bfhi(g.x);
    acc[2] += a * bflo(g.y); acc[3] += a * bfhi(g.y);
    acc[4] += a * bflo(g.z); acc[5] += a * bfhi(g.z);
    acc[6] += a * bflo(g.w); acc[7] += a * bfhi(g.w);
}

// ---------------- scatter v5: L2-resident phases ----------------
// 16-lane groups, 8 ch/lane (16B gathers, 256B contiguous per group per edge).
// PLANAR (layer 1): h = [head][NN][128] planes, blockIdx.y = head.
// !PLANAR (layer 2): h = [NN][HC] node-major, blockIdx.y = 128-ch column slice.
// ACT: 1 = elu, 2 = relu.
template<int ACT, int H, int HC, bool PLANAR>
__global__ __launch_bounds__(128)
void gat_scatter5(const int* __restrict__ row_start, const int* __restrict__ slot_src,
                  const float* __restrict__ exal_t, const float* __restrict__ inv,
                  const u16* __restrict__ h, const float* __restrict__ bias,
                  u16* __restrict__ out) {
    const int grp = threadIdx.x >> 4;          // 0..7
    const int lg  = threadIdx.x & 15;
    const int d   = blockIdx.x * 8 + grp;
    const int y   = blockIdx.y;                // head (l1) or channel slice (l2)
    const int cc  = y * 128 + lg * 8;          // output channel base
    const int s0 = row_start[d], s1 = row_start[d + 1];
    const float* exp_pl = exal_t + (size_t)(PLANAR ? y : 0) * ETOT;
    const u16* hb = PLANAR ? (h + (size_t)y * NN * 128 + lg * 8)
                           : (h + cc);
    const int hstride = PLANAR ? 128 : HC;

    float acc0[8] = {}, acc1[8] = {}, acc2[8] = {}, acc3[8] = {};

    for (int base = s0; base < s1; base += 16) {
        int e = base + lg;
        bool ok = (e < s1);
        int mySrc = 0; float mA = 0.f;
        if (ok) { mySrc = slot_src[e]; mA = exp_pl[e]; }
        int cnt = min(16, s1 - base);
        int j = 0;
        for (; j + 4 <= cnt; j += 4) {
            int sA = __shfl(mySrc, j, 16),     sB = __shfl(mySrc, j + 1, 16);
            int sC = __shfl(mySrc, j + 2, 16), sD = __shfl(mySrc, j + 3, 16);
            float aA = __shfl(mA, j, 16),     aB = __shfl(mA, j + 1, 16);
            float aC = __shfl(mA, j + 2, 16), aD = __shfl(mA, j + 3, 16);
            uint4 gA = *(const uint4*)(hb + (size_t)sA * hstride);
            uint4 gB = *(const uint4*)(hb + (size_t)sB * hstride);
            uint4 gC = *(const uint4*)(hb + (size_t)sC * hstride);
            uint4 gD = *(const uint4*)(hb + (size_t)sD * hstride);
            fma8(acc0, gA, aA); fma8(acc1, gB, aB);
            fma8(acc2, gC, aC); fma8(acc3, gD, aD);
        }
        for (; j < cnt; ++j) {
            int sA = __shfl(mySrc, j, 16);
            float aA = __shfl(mA, j, 16);
            uint4 gA = *(const uint4*)(hb + (size_t)sA * hstride);
            fma8(acc0, gA, aA);
        }
    }

    float sc = inv[(size_t)d * H + (PLANAR ? y : 0)];
    float4 b0 = *(const float4*)(bias + cc);
    float4 b1 = *(const float4*)(bias + cc + 4);
    float bb[8] = { b0.x, b0.y, b0.z, b0.w, b1.x, b1.y, b1.z, b1.w };
    u16 os[8];
#pragma unroll
    for (int k = 0; k < 8; ++k) {
        float v = (acc0[k] + acc1[k]) + (acc2[k] + acc3[k]);
        v = v * sc + bb[k];
        if (ACT == 1) v = (v > 0.f) ? v : (expf(v) - 1.f);   // elu
        else          v = fmaxf(v, 0.f);                      // relu
        os[k] = f2bf(v);
    }
    uint4 q;
    q.x = (u32)os[0] | ((u32)os[1] << 16);
    q.y = (u32)os[2] | ((u32)os[3] << 16);
    q.z = (u32)os[4] | ((u32)os[5] << 16);
    q.w = (u32)os[6] | ((u32)os[7] << 16);
    *(uint4*)(out + (size_t)d * HC + cc) = q;
}

extern "C" void kernel_launch(void* const* d_in, const int* in_sizes, int n_in,
                              void* d_out, int out_size, void* d_ws, size_t ws_size,
                              hipStream_t stream) {
    const float* node      = (const float*)d_in[0];
    const int*   esrc      = (const int*)d_in[1];          // edge_index[0]
    const int*   edst      = ((const int*)d_in[1]) + EE;   // edge_index[1]
    const float* W1        = (const float*)d_in[2];
    const float* att_src1  = (const float*)d_in[3];
    const float* att_dst1  = (const float*)d_in[4];
    const float* b1        = (const float*)d_in[5];
    const float* W2        = (const float*)d_in[6];
    const float* att_src2  = (const float*)d_in[7];
    const float* att_dst2  = (const float*)d_in[8];
    const float* b2        = (const float*)d_in[9];
    const float* fc_w      = (const float*)d_in[10];
    const float* fc_b      = (const float*)d_in[11];
    float* out = (float*)d_out;

    // ---- workspace layout ----
    u16* bufA  = (u16*)d_ws;                        // [NN*HC1]  h1 planes, later h2
    u16* bufB  = bufA + (size_t)NN * HC1;           // [NN*HC1]  x2b, later out2b
    u16* nodeb = bufB + (size_t)NN * HC1;           // [NN*F_IN]
    u16* w1t   = nodeb + (size_t)NN * F_IN;         // [HC1*F_IN]
    u16* w2t   = w1t + (size_t)HC1 * F_IN;          // [HC2*HC1]
    u16* fcwt  = w2t + (size_t)HC2 * HC1;           // [OUT_DIM*OUT_DIM]
    float* exal  = (float*)(fcwt + (size_t)OUT_DIM * OUT_DIM);  // [H1*ETOT] planes
    float* inv   = exal + (size_t)ETOT * H1;        // [NN*H1]
    float* a_s1  = inv + (size_t)NN * H1;           // [NN*H1]
    float* a_d1  = a_s1 + (size_t)NN * H1;
    float* a_s2  = a_d1 + (size_t)NN * H1;          // [NN]
    float* a_d2  = a_s2 + NN;
    int* deg       = (int*)(a_d2 + NN);
    int* cursor    = deg + NN;
    int* row_start = cursor + NN;                   // [NN+1]
    int* slot_src  = row_start + NN + 8;            // [ETOT]

    // ---- conversions ----
    f32_to_bf16_kernel<<<(NN * F_IN + 255) / 256, 256, 0, stream>>>(node, nodeb, NN * F_IN);
    transpose_bf16_kernel<<<dim3(HC1 / 16, F_IN / 16), dim3(16, 16), 0, stream>>>(W1, w1t, F_IN, HC1);
    transpose_bf16_kernel<<<dim3(HC2 / 16, HC1 / 16), dim3(16, 16), 0, stream>>>(W2, w2t, HC1, HC2);
    transpose_bf16_kernel<<<dim3(OUT_DIM / 16, OUT_DIM / 16), dim3(16, 16), 0, stream>>>(fc_w, fcwt, OUT_DIM, OUT_DIM);

    // ---- CSR build ----
    hipMemsetAsync(deg, 0, 2 * NN * sizeof(int), stream);  // deg + cursor
    hist_kernel<<<(ETOT + 255) / 256, 256, 0, stream>>>(edst, deg);
    scan_kernel<<<1, 1024, 0, stream>>>(deg, row_start);
    fill_kernel<<<(ETOT + 255) / 256, 256, 0, stream>>>(esrc, edst, row_start, cursor, slot_src);

    // ---- layer 1 (h1 stored as head-major planes) ----
    gemm_bf16<0, 1><<<dim3(HC1 / 128, (NN + 127) / 128), 128, 0, stream>>>(nodeb, w1t, nullptr, bufA, NN, HC1, F_IN);
    att_logits3<H1, C1, true><<<NN / 2, 128, 0, stream>>>(bufA, att_src1, att_dst1, a_s1, a_d1);
    att_alpha3<H1><<<NN / 2, 128, 0, stream>>>(row_start, slot_src, a_s1, a_d1, exal, inv);
    gat_scatter5<1, H1, HC1, true><<<dim3(NN / 8, H1), 128, 0, stream>>>(row_start, slot_src, exal, inv, bufA, b1, bufB);

    // ---- layer 2 (node-major, channel-slice phases) ----
    gemm_bf16<0, 0><<<dim3(HC2 / 128, (NN + 127) / 128), 128, 0, stream>>>(bufB, w2t, nullptr, bufA, NN, HC2, HC1);
    att_logits3<H2, C2, false><<<NN / 2, 128, 0, stream>>>(bufA, att_src2, att_dst2, a_s2, a_d2);
    att_alpha3<H2><<<NN / 2, 128, 0, stream>>>(row_start, slot_src, a_s2, a_d2, exal, inv);
    gat_scatter5<2, H2, HC2, false><<<dim3(NN / 8, HC2 / 128), 128, 0, stream>>>(row_start, slot_src, exal, inv, bufA, b2, bufB);

    // ---- fc: out = relu(out2 @ fc_w + fc_b), f32 out ----
    gemm_bf16<1, 0><<<dim3(OUT_DIM / 128, (NN + 127) / 128), 128, 0, stream>>>(bufB, fcwt, fc_b, out, NN, OUT_DIM, OUT_DIM);
}

// Round 12
// 260.309 us; speedup vs baseline: 1.0226x; 1.0083x over previous
//
#include <hip/hip_runtime.h>
#include <hip/hip_bf16.h>
#include <cstddef>
#include <cstdint>

// Problem constants
#define NN 10000
#define EE 160000
#define ETOT (EE + NN)
#define F_IN 128
#define H1 10
#define C1 128
#define HC1 1280
#define H2 1
#define C2 1024
#define HC2 1024
#define OUT_DIM 1024

typedef __attribute__((ext_vector_type(4))) float f32x4;
typedef __attribute__((ext_vector_type(8))) short s16x8;
typedef unsigned int u32;
typedef unsigned short u16;

__device__ __forceinline__ float bf2f(u16 v) {
    union { u32 u; float f; } x; x.u = ((u32)v) << 16; return x.f;
}
__device__ __forceinline__ float bflo(u32 q) {   // low bf16 of a packed u32
    union { u32 u; float f; } x; x.u = q << 16; return x.f;
}
__device__ __forceinline__ float bfhi(u32 q) {   // high bf16 of a packed u32
    union { u32 u; float f; } x; x.u = q & 0xffff0000u; return x.f;
}
__device__ __forceinline__ u16 f2bf(float f) {
    union { float f; u32 u; } x; x.f = f;
    u32 u = x.u;
    u32 r = (u + 0x7fffu + ((u >> 16) & 1u)) >> 16;   // RNE
    return (u16)r;
}

__device__ __forceinline__ void gld16(const void* g, void* l) {
    __builtin_amdgcn_global_load_lds((const __attribute__((address_space(1))) u32*)g,
                                     (__attribute__((address_space(3))) u32*)l, 16, 0, 0);
}

// Producer-side drain of async global_load_lds BEFORE the barrier (round-6 race fix).
__device__ __forceinline__ void vm_drain() {
    asm volatile("s_waitcnt vmcnt(0)" ::: "memory");
}

// ---------------- conversions ----------------
__global__ void f32_to_bf16_kernel(const float* __restrict__ in, u16* __restrict__ out, int n) {
    int i = blockIdx.x * 256 + threadIdx.x;
    if (i < n) out[i] = f2bf(in[i]);
}

// in: [K][N] row-major f32; out: [N][K] bf16.
__global__ void transpose_bf16_kernel(const float* __restrict__ in, u16* __restrict__ out,
                                      int K, int N) {
    __shared__ u16 t[16][17];
    int n0 = blockIdx.x * 16, k0 = blockIdx.y * 16;
    t[threadIdx.y][threadIdx.x] = f2bf(in[(size_t)(k0 + threadIdx.y) * N + n0 + threadIdx.x]);
    __syncthreads();
    out[(size_t)(n0 + threadIdx.y) * K + k0 + threadIdx.x] = t[threadIdx.x][threadIdx.y];
}

// ---------------- CSR build ----------------
__global__ void hist_kernel(const int* __restrict__ edst, int* __restrict__ deg) {
    int e = blockIdx.x * 256 + threadIdx.x;
    if (e >= ETOT) return;
    int d = (e < EE) ? edst[e] : (e - EE);
    atomicAdd(&deg[d], 1);
}

// shfl-based single-block scan (1024 threads)
__global__ void scan_kernel(const int* __restrict__ deg, int* __restrict__ row_start) {
    __shared__ int wsum[16];
    const int tid = threadIdx.x;
    const int lane = tid & 63;
    const int wid = tid >> 6;
    int carry = 0;
    for (int base = 0; base < NN; base += 1024) {
        int i = base + tid;
        int v = (i < NN) ? deg[i] : 0;
        int x = v;
#pragma unroll
        for (int o = 1; o < 64; o <<= 1) {
            int t = __shfl_up(x, o);
            if (lane >= o) x += t;
        }
        if (lane == 63) wsum[wid] = x;
        __syncthreads();
        if (wid == 0) {
            int w = (lane < 16) ? wsum[lane] : 0;
#pragma unroll
            for (int o = 1; o < 16; o <<= 1) {
                int t = __shfl_up(w, o);
                if (lane >= o) w += t;
            }
            if (lane < 16) wsum[lane] = w;
        }
        __syncthreads();
        int woff = (wid == 0) ? 0 : wsum[wid - 1];
        if (i < NN) row_start[i] = carry + woff + x - v;   // exclusive
        carry += wsum[15];
        __syncthreads();
    }
    if (tid == 0) row_start[NN] = carry;
}

__global__ void fill_kernel(const int* __restrict__ esrc, const int* __restrict__ edst,
                            const int* __restrict__ row_start, int* __restrict__ cursor,
                            int* __restrict__ slot_src) {
    int e = blockIdx.x * 256 + threadIdx.x;
    if (e >= ETOT) return;
    int s, d;
    if (e < EE) { s = esrc[e]; d = edst[e]; }
    else        { s = d = e - EE; }
    int pos = atomicAdd(&cursor[d], 1);
    slot_src[row_start[d] + pos] = s;
}

// ---------------- bf16 MFMA GEMM: C = A[MxK] * Bt[NxK]^T ----------------
// R8 config (best measured): 128x128 tile, 4 waves (2x2), 16x16x32 MFMA, BK=32,
// double-buffered LDS prefetch + explicit producer vmcnt drain, bijective XCD
// swizzle. This shape (M=10000, N~1-1.3k) sits ON the m97-structure shape curve
// at ~520 TF; 4 alternative schedules (R9-R11) all plateaued at 45-52us.
// BIAS_RELU==1: +bias, relu, f32 out. HEADMAJ==1: bf16 head-major planes
// [n/128][M][128]. LOGITS==1: fused attention logits — per-row dot with
// att_s/att_d accumulated via atomicAdd into as_out/ad_out[m*HLOG + head]
// (head = bn>>7 when HEADMAJ else 0). Saves the separate logits pass.
template<int BIAS_RELU, int HEADMAJ, int LOGITS, int HLOG>
__global__ __launch_bounds__(256, 2)
void gemm_bf16(const u16* __restrict__ A, const u16* __restrict__ Bt,
               const float* __restrict__ bias, void* __restrict__ Cout,
               int M, int N, int K,
               const float* __restrict__ att_s, const float* __restrict__ att_d,
               float* __restrict__ as_out, float* __restrict__ ad_out) {
    __shared__ u16 Als[2][128 * 32];
    __shared__ u16 Bls[2][128 * 32];
    const int tid  = threadIdx.x;
    const int wave = tid >> 6;
    const int lane = tid & 63;

    // bijective XCD swizzle
    const int nwg = gridDim.x * gridDim.y;
    const int bid = blockIdx.y * gridDim.x + blockIdx.x;
    const int q = nwg >> 3, r = nwg & 7;
    const int xcd = bid & 7, idx = bid >> 3;
    const int swz = (xcd < r ? xcd * (q + 1) : r * (q + 1) + (xcd - r) * q) + idx;
    const int bm = (swz / gridDim.x) * 128;
    const int bn = (swz % gridDim.x) * 128;

    const int wr = wave >> 1, wc = wave & 1;   // 2x2 waves, each 64x64
    const int lr = lane & 15;
    const int kc = lane >> 4;

    f32x4 acc[4][4] = {};

    const int srow = tid >> 2;
    const int scol = (tid & 3) * 8;
    int arow0 = bm + srow;       if (arow0 >= M) arow0 = M - 1;
    int arow1 = bm + 64 + srow;  if (arow1 >= M) arow1 = M - 1;
    const int brow0 = bn + srow;
    const int brow1 = bn + 64 + srow;

    const u16* aP0 = A  + (size_t)arow0 * K + scol;
    const u16* aP1 = A  + (size_t)arow1 * K + scol;
    const u16* bP0 = Bt + (size_t)brow0 * K + scol;
    const u16* bP1 = Bt + (size_t)brow1 * K + scol;

    // prologue: stage tile 0 into buf 0
    gld16(aP0, &Als[0][(size_t)wave * 512]);
    gld16(aP1, &Als[0][2048 + (size_t)wave * 512]);
    gld16(bP0, &Bls[0][(size_t)wave * 512]);
    gld16(bP1, &Bls[0][2048 + (size_t)wave * 512]);
    vm_drain();
    __syncthreads();

    int cur = 0;
    for (int k0 = 0; k0 < K; k0 += 32) {
        if (k0 + 32 < K) {
            int nxt = cur ^ 1;
            gld16(aP0 + k0 + 32, &Als[nxt][(size_t)wave * 512]);
            gld16(aP1 + k0 + 32, &Als[nxt][2048 + (size_t)wave * 512]);
            gld16(bP0 + k0 + 32, &Bls[nxt][(size_t)wave * 512]);
            gld16(bP1 + k0 + 32, &Bls[nxt][2048 + (size_t)wave * 512]);
        }

        s16x8 af[4], bg[4];
#pragma unroll
        for (int i = 0; i < 4; ++i)
            af[i] = *(const s16x8*)&Als[cur][(wr * 64 + i * 16 + lr) * 32 + kc * 8];
#pragma unroll
        for (int j = 0; j < 4; ++j)
            bg[j] = *(const s16x8*)&Bls[cur][(wc * 64 + j * 16 + lr) * 32 + kc * 8];
#pragma unroll
        for (int i = 0; i < 4; ++i)
#pragma unroll
            for (int j = 0; j < 4; ++j)
                acc[i][j] = __builtin_amdgcn_mfma_f32_16x16x32_bf16(af[i], bg[j], acc[i][j], 0, 0, 0);

        vm_drain();      // prefetch visible to ALL waves before the barrier
        __syncthreads();
        cur ^= 1;
    }

    // ---- fused attention logits (per-row dot with att vectors) ----
    if (LOGITS) {
        // att values for this thread's 4 columns (same for every row it owns)
        float asv[4], adv[4];
#pragma unroll
        for (int j = 0; j < 4; ++j) {
            int n = bn + wc * 64 + j * 16 + lr;
            asv[j] = att_s[n];
            adv[j] = att_d[n];
        }
        const int hd = HEADMAJ ? (bn >> 7) : 0;
#pragma unroll
        for (int i = 0; i < 4; ++i) {
#pragma unroll
            for (int r2 = 0; r2 < 4; ++r2) {
                float ps = 0.f, pd = 0.f;
#pragma unroll
                for (int j = 0; j < 4; ++j) {
                    float v = acc[i][j][r2];
                    ps += v * asv[j];
                    pd += v * adv[j];
                }
                // reduce across the 16 lanes (lr) sharing this kc group
#pragma unroll
                for (int msk = 8; msk; msk >>= 1) {
                    ps += __shfl_xor(ps, msk);
                    pd += __shfl_xor(pd, msk);
                }
                int m = bm + wr * 64 + i * 16 + kc * 4 + r2;
                if (lr == 0 && m < M) {
                    atomicAdd(&as_out[(size_t)m * HLOG + hd], ps);
                    atomicAdd(&ad_out[(size_t)m * HLOG + hd], pd);
                }
            }
        }
    }

    // C/D layout: col = lane&15, row = (lane>>4)*4 + reg
#pragma unroll
    for (int i = 0; i < 4; ++i) {
#pragma unroll
        for (int r2 = 0; r2 < 4; ++r2) {
            int m = bm + wr * 64 + i * 16 + kc * 4 + r2;
            if (m >= M) continue;
#pragma unroll
            for (int j = 0; j < 4; ++j) {
                int n = bn + wc * 64 + j * 16 + lr;
                float v = acc[i][j][r2];
                if (BIAS_RELU) {
                    v += bias[n];
                    v = fmaxf(v, 0.f);
                    ((float*)Cout)[(size_t)m * N + n] = v;
                } else if (HEADMAJ) {
                    ((u16*)Cout)[(size_t)(n >> 7) * NN * 128 + (size_t)m * 128 + (n & 127)] = f2bf(v);
                } else {
                    ((u16*)Cout)[(size_t)m * N + n] = f2bf(v);
                }
            }
        }
    }
}

// ---------------- alpha: unnormalized exp (TRANSPOSED planes [H][ETOT]) + inv sums ----
template<int H>
__global__ __launch_bounds__(128)
void att_alpha3(const int* __restrict__ row_start, const int* __restrict__ slot_src,
                const float* __restrict__ a_s, const float* __restrict__ a_d,
                float* __restrict__ exal_t, float* __restrict__ inv) {
    const int d = blockIdx.x * 2 + (threadIdx.x >> 6);
    const int lane = threadIdx.x & 63;
    const int s0 = row_start[d], s1 = row_start[d + 1];
    float ad[H];
#pragma unroll
    for (int hd = 0; hd < H; ++hd) ad[hd] = a_d[(size_t)d * H + hd];
    float sums[H];
#pragma unroll
    for (int hd = 0; hd < H; ++hd) sums[hd] = 0.f;

    for (int base = s0; base < s1; base += 64) {
        int e = base + lane;
        bool ok = (e < s1);
        int src = ok ? slot_src[e] : 0;
        float as[H];
        if constexpr (H == 1) {
            as[0] = ok ? a_s[src] : 0.f;
        } else {
            const float2* asp = (const float2*)(a_s + (size_t)src * H);
#pragma unroll
            for (int i = 0; i < H / 2; ++i) {
                float2 q = ok ? asp[i] : make_float2(0.f, 0.f);
                as[2 * i] = q.x; as[2 * i + 1] = q.y;
            }
        }
#pragma unroll
        for (int hd = 0; hd < H; ++hd) {
            float t = as[hd] + ad[hd];
            t = (t > 0.f) ? t : 0.2f * t;          // leaky_relu 0.2
            float x = ok ? expf(t) : 0.f;          // logits small by construction
            sums[hd] += x;
            if (ok) exal_t[(size_t)hd * ETOT + e] = x;   // coalesced per plane
        }
    }
#pragma unroll
    for (int hd = 0; hd < H; ++hd) {
#pragma unroll
        for (int off = 32; off; off >>= 1) sums[hd] += __shfl_down(sums[hd], off);
    }
    if (lane == 0) {
#pragma unroll
        for (int hd = 0; hd < H; ++hd) inv[(size_t)d * H + hd] = 1.f / (sums[hd] + 1e-16f);
    }
}

// helper: accumulate 8 channels from a uint4 of packed bf16
__device__ __forceinline__ void fma8(float* acc, uint4 g, float a) {
    acc[0] += a * bflo(g.x); acc[1] += a * bfhi(g.x);
    acc[2] += a * bflo(g.y); acc[3] += a * bfhi(g.y);
    acc[4] += a * bflo(g.z); acc[5] += a * bfhi(g.z);
    acc[6] += a * bflo(g.w); acc[7] += a * bfhi(g.w);
}

// ---------------- scatter v5: L2-resident phases ----------------
// 16-lane groups, 8 ch/lane (16B gathers, 256B contiguous per group per edge).
// PLANAR (layer 1): h = [head][NN][128] planes, blockIdx.y = head.
// !PLANAR (layer 2): h = [NN][HC] node-major, blockIdx.y = 128-ch column slice.
// ACT: 1 = elu, 2 = relu.
template<int ACT, int H, int HC, bool PLANAR>
__global__ __launch_bounds__(128)
void gat_scatter5(const int* __restrict__ row_start, const int* __restrict__ slot_src,
                  const float* __restrict__ exal_t, const float* __restrict__ inv,
                  const u16* __restrict__ h, const float* __restrict__ bias,
                  u16* __restrict__ out) {
    const int grp = threadIdx.x >> 4;          // 0..7
    const int lg  = threadIdx.x & 15;
    const int d   = blockIdx.x * 8 + grp;
    const int y   = blockIdx.y;                // head (l1) or channel slice (l2)
    const int cc  = y * 128 + lg * 8;          // output channel base
    const int s0 = row_start[d], s1 = row_start[d + 1];
    const float* exp_pl = exal_t + (size_t)(PLANAR ? y : 0) * ETOT;
    const u16* hb = PLANAR ? (h + (size_t)y * NN * 128 + lg * 8)
                           : (h + cc);
    const int hstride = PLANAR ? 128 : HC;

    float acc0[8] = {}, acc1[8] = {}, acc2[8] = {}, acc3[8] = {};

    for (int base = s0; base < s1; base += 16) {
        int e = base + lg;
        bool ok = (e < s1);
        int mySrc = 0; float mA = 0.f;
        if (ok) { mySrc = slot_src[e]; mA = exp_pl[e]; }
        int cnt = min(16, s1 - base);
        int j = 0;
        for (; j + 4 <= cnt; j += 4) {
            int sA = __shfl(mySrc, j, 16),     sB = __shfl(mySrc, j + 1, 16);
            int sC = __shfl(mySrc, j + 2, 16), sD = __shfl(mySrc, j + 3, 16);
            float aA = __shfl(mA, j, 16),     aB = __shfl(mA, j + 1, 16);
            float aC = __shfl(mA, j + 2, 16), aD = __shfl(mA, j + 3, 16);
            uint4 gA = *(const uint4*)(hb + (size_t)sA * hstride);
            uint4 gB = *(const uint4*)(hb + (size_t)sB * hstride);
            uint4 gC = *(const uint4*)(hb + (size_t)sC * hstride);
            uint4 gD = *(const uint4*)(hb + (size_t)sD * hstride);
            fma8(acc0, gA, aA); fma8(acc1, gB, aB);
            fma8(acc2, gC, aC); fma8(acc3, gD, aD);
        }
        for (; j < cnt; ++j) {
            int sA = __shfl(mySrc, j, 16);
            float aA = __shfl(mA, j, 16);
            uint4 gA = *(const uint4*)(hb + (size_t)sA * hstride);
            fma8(acc0, gA, aA);
        }
    }

    float sc = inv[(size_t)d * H + (PLANAR ? y : 0)];
    float4 b0 = *(const float4*)(bias + cc);
    float4 b1 = *(const float4*)(bias + cc + 4);
    float bb[8] = { b0.x, b0.y, b0.z, b0.w, b1.x, b1.y, b1.z, b1.w };
    u16 os[8];
#pragma unroll
    for (int k = 0; k < 8; ++k) {
        float v = (acc0[k] + acc1[k]) + (acc2[k] + acc3[k]);
        v = v * sc + bb[k];
        if (ACT == 1) v = (v > 0.f) ? v : (expf(v) - 1.f);   // elu
        else          v = fmaxf(v, 0.f);                      // relu
        os[k] = f2bf(v);
    }
    uint4 q;
    q.x = (u32)os[0] | ((u32)os[1] << 16);
    q.y = (u32)os[2] | ((u32)os[3] << 16);
    q.z = (u32)os[4] | ((u32)os[5] << 16);
    q.w = (u32)os[6] | ((u32)os[7] << 16);
    *(uint4*)(out + (size_t)d * HC + cc) = q;
}

extern "C" void kernel_launch(void* const* d_in, const int* in_sizes, int n_in,
                              void* d_out, int out_size, void* d_ws, size_t ws_size,
                              hipStream_t stream) {
    const float* node      = (const float*)d_in[0];
    const int*   esrc      = (const int*)d_in[1];          // edge_index[0]
    const int*   edst      = ((const int*)d_in[1]) + EE;   // edge_index[1]
    const float* W1        = (const float*)d_in[2];
    const float* att_src1  = (const float*)d_in[3];
    const float* att_dst1  = (const float*)d_in[4];
    const float* b1        = (const float*)d_in[5];
    const float* W2        = (const float*)d_in[6];
    const float* att_src2  = (const float*)d_in[7];
    const float* att_dst2  = (const float*)d_in[8];
    const float* b2        = (const float*)d_in[9];
    const float* fc_w      = (const float*)d_in[10];
    const float* fc_b      = (const float*)d_in[11];
    float* out = (float*)d_out;

    // ---- workspace layout ----
    u16* bufA  = (u16*)d_ws;                        // [NN*HC1]  h1 planes, later h2
    u16* bufB  = bufA + (size_t)NN * HC1;           // [NN*HC1]  x2b, later out2b
    u16* nodeb = bufB + (size_t)NN * HC1;           // [NN*F_IN]
    u16* w1t   = nodeb + (size_t)NN * F_IN;         // [HC1*F_IN]
    u16* w2t   = w1t + (size_t)HC1 * F_IN;          // [HC2*HC1]
    u16* fcwt  = w2t + (size_t)HC2 * HC1;           // [OUT_DIM*OUT_DIM]
    float* exal  = (float*)(fcwt + (size_t)OUT_DIM * OUT_DIM);  // [H1*ETOT] planes
    float* inv   = exal + (size_t)ETOT * H1;        // [NN*H1]
    // zero-init region (single memset): a_s1, a_d1, a_s2, a_d2, deg, cursor
    float* a_s1  = inv + (size_t)NN * H1;           // [NN*H1]
    float* a_d1  = a_s1 + (size_t)NN * H1;          // [NN*H1]
    float* a_s2  = a_d1 + (size_t)NN * H1;          // [NN]
    float* a_d2  = a_s2 + NN;                       // [NN]
    int* deg       = (int*)(a_d2 + NN);             // [NN]
    int* cursor    = deg + NN;                      // [NN]
    int* row_start = cursor + NN;                   // [NN+1]
    int* slot_src  = row_start + NN + 8;            // [ETOT]
    const size_t zero_bytes = ((size_t)NN * H1 * 2 + NN * 2) * sizeof(float)
                            + (size_t)NN * 2 * sizeof(int);

    // ---- conversions ----
    f32_to_bf16_kernel<<<(NN * F_IN + 255) / 256, 256, 0, stream>>>(node, nodeb, NN * F_IN);
    transpose_bf16_kernel<<<dim3(HC1 / 16, F_IN / 16), dim3(16, 16), 0, stream>>>(W1, w1t, F_IN, HC1);
    transpose_bf16_kernel<<<dim3(HC2 / 16, HC1 / 16), dim3(16, 16), 0, stream>>>(W2, w2t, HC1, HC2);
    transpose_bf16_kernel<<<dim3(OUT_DIM / 16, OUT_DIM / 16), dim3(16, 16), 0, stream>>>(fc_w, fcwt, OUT_DIM, OUT_DIM);

    // ---- zero logits accumulators + CSR counters (one memset) ----
    hipMemsetAsync(a_s1, 0, zero_bytes, stream);

    // ---- CSR build ----
    hist_kernel<<<(ETOT + 255) / 256, 256, 0, stream>>>(edst, deg);
    scan_kernel<<<1, 1024, 0, stream>>>(deg, row_start);
    fill_kernel<<<(ETOT + 255) / 256, 256, 0, stream>>>(esrc, edst, row_start, cursor, slot_src);

    // ---- layer 1: GEMM (head-major planes) + fused logits ----
    gemm_bf16<0, 1, 1, H1><<<dim3(HC1 / 128, (NN + 127) / 128), 256, 0, stream>>>(
        nodeb, w1t, nullptr, bufA, NN, HC1, F_IN, att_src1, att_dst1, a_s1, a_d1);
    att_alpha3<H1><<<NN / 2, 128, 0, stream>>>(row_start, slot_src, a_s1, a_d1, exal, inv);
    gat_scatter5<1, H1, HC1, true><<<dim3(NN / 8, H1), 128, 0, stream>>>(row_start, slot_src, exal, inv, bufA, b1, bufB);

    // ---- layer 2: GEMM (node-major) + fused logits ----
    gemm_bf16<0, 0, 1, H2><<<dim3(HC2 / 128, (NN + 127) / 128), 256, 0, stream>>>(
        bufB, w2t, nullptr, bufA, NN, HC2, HC1, att_src2, att_dst2, a_s2, a_d2);
    att_alpha3<H2><<<NN / 2, 128, 0, stream>>>(row_start, slot_src, a_s2, a_d2, exal, inv);
    gat_scatter5<2, H2, HC2, false><<<dim3(NN / 8, HC2 / 128), 128, 0, stream>>>(row_start, slot_src, exal, inv, bufA, b2, bufB);

    // ---- fc: out = relu(out2 @ fc_w + fc_b), f32 out ----
    gemm_bf16<1, 0, 0, 1><<<dim3(OUT_DIM / 128, (NN + 127) / 128), 256, 0, stream>>>(
        bufB, fcwt, fc_b, out, NN, OUT_DIM, OUT_DIM, nullptr, nullptr, nullptr, nullptr);
}

// Round 13
// 234.681 us; speedup vs baseline: 1.1343x; 1.1092x over previous
//
#include <hip/hip_runtime.h>
#include <hip/hip_bf16.h>
#include <cstddef>
#include <cstdint>

// Problem constants
#define NN 10000
#define EE 160000
#define ETOT (EE + NN)
#define F_IN 128
#define H1 10
#define C1 128
#define HC1 1280
#define H2 1
#define C2 1024
#define HC2 1024
#define OUT_DIM 1024

typedef __attribute__((ext_vector_type(4))) float f32x4;
typedef __attribute__((ext_vector_type(8))) short s16x8;
typedef unsigned int u32;
typedef unsigned short u16;

__device__ __forceinline__ float bf2f(u16 v) {
    union { u32 u; float f; } x; x.u = ((u32)v) << 16; return x.f;
}
__device__ __forceinline__ float bflo(u32 q) {   // low bf16 of a packed u32
    union { u32 u; float f; } x; x.u = q << 16; return x.f;
}
__device__ __forceinline__ float bfhi(u32 q) {   // high bf16 of a packed u32
    union { u32 u; float f; } x; x.u = q & 0xffff0000u; return x.f;
}
__device__ __forceinline__ u16 f2bf(float f) {
    union { float f; u32 u; } x; x.f = f;
    u32 u = x.u;
    u32 r = (u + 0x7fffu + ((u >> 16) & 1u)) >> 16;   // RNE
    return (u16)r;
}

__device__ __forceinline__ void gld16(const void* g, void* l) {
    __builtin_amdgcn_global_load_lds((const __attribute__((address_space(1))) u32*)g,
                                     (__attribute__((address_space(3))) u32*)l, 16, 0, 0);
}

// Producer-side drain of async global_load_lds BEFORE the barrier (round-6 race fix).
__device__ __forceinline__ void vm_drain() {
    asm volatile("s_waitcnt vmcnt(0)" ::: "memory");
}

// ---------------- conversions ----------------
__global__ void f32_to_bf16_kernel(const float* __restrict__ in, u16* __restrict__ out, int n) {
    int i = blockIdx.x * 256 + threadIdx.x;
    if (i < n) out[i] = f2bf(in[i]);
}

// in: [K][N] row-major f32; out: [N][K] bf16.
__global__ void transpose_bf16_kernel(const float* __restrict__ in, u16* __restrict__ out,
                                      int K, int N) {
    __shared__ u16 t[16][17];
    int n0 = blockIdx.x * 16, k0 = blockIdx.y * 16;
    t[threadIdx.y][threadIdx.x] = f2bf(in[(size_t)(k0 + threadIdx.y) * N + n0 + threadIdx.x]);
    __syncthreads();
    out[(size_t)(n0 + threadIdx.y) * K + k0 + threadIdx.x] = t[threadIdx.x][threadIdx.y];
}

// ---------------- CSR build ----------------
__global__ void hist_kernel(const int* __restrict__ edst, int* __restrict__ deg) {
    int e = blockIdx.x * 256 + threadIdx.x;
    if (e >= ETOT) return;
    int d = (e < EE) ? edst[e] : (e - EE);
    atomicAdd(&deg[d], 1);
}

// shfl-based single-block scan (1024 threads)
__global__ void scan_kernel(const int* __restrict__ deg, int* __restrict__ row_start) {
    __shared__ int wsum[16];
    const int tid = threadIdx.x;
    const int lane = tid & 63;
    const int wid = tid >> 6;
    int carry = 0;
    for (int base = 0; base < NN; base += 1024) {
        int i = base + tid;
        int v = (i < NN) ? deg[i] : 0;
        int x = v;
#pragma unroll
        for (int o = 1; o < 64; o <<= 1) {
            int t = __shfl_up(x, o);
            if (lane >= o) x += t;
        }
        if (lane == 63) wsum[wid] = x;
        __syncthreads();
        if (wid == 0) {
            int w = (lane < 16) ? wsum[lane] : 0;
#pragma unroll
            for (int o = 1; o < 16; o <<= 1) {
                int t = __shfl_up(w, o);
                if (lane >= o) w += t;
            }
            if (lane < 16) wsum[lane] = w;
        }
        __syncthreads();
        int woff = (wid == 0) ? 0 : wsum[wid - 1];
        if (i < NN) row_start[i] = carry + woff + x - v;   // exclusive
        carry += wsum[15];
        __syncthreads();
    }
    if (tid == 0) row_start[NN] = carry;
}

__global__ void fill_kernel(const int* __restrict__ esrc, const int* __restrict__ edst,
                            const int* __restrict__ row_start, int* __restrict__ cursor,
                            int* __restrict__ slot_src) {
    int e = blockIdx.x * 256 + threadIdx.x;
    if (e >= ETOT) return;
    int s, d;
    if (e < EE) { s = esrc[e]; d = edst[e]; }
    else        { s = d = e - EE; }
    int pos = atomicAdd(&cursor[d], 1);
    slot_src[row_start[d] + pos] = s;
}

// ---------------- bf16 MFMA GEMM: C = A[MxK] * Bt[NxK]^T ----------------
// R8 config (best measured): 128x128 tile, 4 waves (2x2), 16x16x32 MFMA, BK=32,
// double-buffered LDS prefetch + explicit producer vmcnt drain, bijective XCD
// swizzle. BIAS_RELU==1: +bias, relu, f32 out. HEADMAJ==1: bf16 head-major
// planes [n/128][M][128].
template<int BIAS_RELU, int HEADMAJ>
__global__ __launch_bounds__(256, 2)
void gemm_bf16(const u16* __restrict__ A, const u16* __restrict__ Bt,
               const float* __restrict__ bias, void* __restrict__ Cout,
               int M, int N, int K) {
    __shared__ u16 Als[2][128 * 32];
    __shared__ u16 Bls[2][128 * 32];
    const int tid  = threadIdx.x;
    const int wave = tid >> 6;
    const int lane = tid & 63;

    // bijective XCD swizzle
    const int nwg = gridDim.x * gridDim.y;
    const int bid = blockIdx.y * gridDim.x + blockIdx.x;
    const int q = nwg >> 3, r = nwg & 7;
    const int xcd = bid & 7, idx = bid >> 3;
    const int swz = (xcd < r ? xcd * (q + 1) : r * (q + 1) + (xcd - r) * q) + idx;
    const int bm = (swz / gridDim.x) * 128;
    const int bn = (swz % gridDim.x) * 128;

    const int wr = wave >> 1, wc = wave & 1;   // 2x2 waves, each 64x64
    const int lr = lane & 15;
    const int kc = lane >> 4;

    f32x4 acc[4][4] = {};

    const int srow = tid >> 2;
    const int scol = (tid & 3) * 8;
    int arow0 = bm + srow;       if (arow0 >= M) arow0 = M - 1;
    int arow1 = bm + 64 + srow;  if (arow1 >= M) arow1 = M - 1;
    const int brow0 = bn + srow;
    const int brow1 = bn + 64 + srow;

    const u16* aP0 = A  + (size_t)arow0 * K + scol;
    const u16* aP1 = A  + (size_t)arow1 * K + scol;
    const u16* bP0 = Bt + (size_t)brow0 * K + scol;
    const u16* bP1 = Bt + (size_t)brow1 * K + scol;

    // prologue: stage tile 0 into buf 0
    gld16(aP0, &Als[0][(size_t)wave * 512]);
    gld16(aP1, &Als[0][2048 + (size_t)wave * 512]);
    gld16(bP0, &Bls[0][(size_t)wave * 512]);
    gld16(bP1, &Bls[0][2048 + (size_t)wave * 512]);
    vm_drain();
    __syncthreads();

    int cur = 0;
    for (int k0 = 0; k0 < K; k0 += 32) {
        if (k0 + 32 < K) {
            int nxt = cur ^ 1;
            gld16(aP0 + k0 + 32, &Als[nxt][(size_t)wave * 512]);
            gld16(aP1 + k0 + 32, &Als[nxt][2048 + (size_t)wave * 512]);
            gld16(bP0 + k0 + 32, &Bls[nxt][(size_t)wave * 512]);
            gld16(bP1 + k0 + 32, &Bls[nxt][2048 + (size_t)wave * 512]);
        }

        s16x8 af[4], bg[4];
#pragma unroll
        for (int i = 0; i < 4; ++i)
            af[i] = *(const s16x8*)&Als[cur][(wr * 64 + i * 16 + lr) * 32 + kc * 8];
#pragma unroll
        for (int j = 0; j < 4; ++j)
            bg[j] = *(const s16x8*)&Bls[cur][(wc * 64 + j * 16 + lr) * 32 + kc * 8];
#pragma unroll
        for (int i = 0; i < 4; ++i)
#pragma unroll
            for (int j = 0; j < 4; ++j)
                acc[i][j] = __builtin_amdgcn_mfma_f32_16x16x32_bf16(af[i], bg[j], acc[i][j], 0, 0, 0);

        vm_drain();      // prefetch visible to ALL waves before the barrier
        __syncthreads();
        cur ^= 1;
    }

    // C/D layout: col = lane&15, row = (lane>>4)*4 + reg
#pragma unroll
    for (int i = 0; i < 4; ++i) {
#pragma unroll
        for (int r2 = 0; r2 < 4; ++r2) {
            int m = bm + wr * 64 + i * 16 + kc * 4 + r2;
            if (m >= M) continue;
#pragma unroll
            for (int j = 0; j < 4; ++j) {
                int n = bn + wc * 64 + j * 16 + lr;
                float v = acc[i][j][r2];
                if (BIAS_RELU) {
                    v += bias[n];
                    v = fmaxf(v, 0.f);
                    ((float*)Cout)[(size_t)m * N + n] = v;
                } else if (HEADMAJ) {
                    ((u16*)Cout)[(size_t)(n >> 7) * NN * 128 + (size_t)m * 128 + (n & 127)] = f2bf(v);
                } else {
                    ((u16*)Cout)[(size_t)m * N + n] = f2bf(v);
                }
            }
        }
    }
}

// ---------------- logits: 4 ch/lane vector loads ----------------
// PLANAR: h stored as [head][NN][C] planes. H even: half-wave per head pair member.
template<int H, int C, bool PLANAR>
__global__ __launch_bounds__(128)
void att_logits3(const u16* __restrict__ h, const float* __restrict__ att_s,
                 const float* __restrict__ att_d, float* __restrict__ a_s,
                 float* __restrict__ a_d) {
    const int n = blockIdx.x * 2 + (threadIdx.x >> 6);
    const int lane = threadIdx.x & 63;
    if constexpr (H == 1) {
        const u16* row = h + (size_t)n * C;
        float ps = 0.f, pd = 0.f;
        for (int c = lane * 4; c < C; c += 256) {
            uint2 q = *(const uint2*)(row + c);
            float4 s = *(const float4*)(att_s + c);
            float4 dd = *(const float4*)(att_d + c);
            float v0 = bflo(q.x), v1 = bfhi(q.x), v2 = bflo(q.y), v3 = bfhi(q.y);
            ps += v0 * s.x + v1 * s.y + v2 * s.z + v3 * s.w;
            pd += v0 * dd.x + v1 * dd.y + v2 * dd.z + v3 * dd.w;
        }
#pragma unroll
        for (int off = 32; off; off >>= 1) {
            ps += __shfl_down(ps, off);
            pd += __shfl_down(pd, off);
        }
        if (lane == 0) { a_s[n] = ps; a_d[n] = pd; }
    } else {
        const int sub = lane >> 5;        // which head of the pair
        const int lg  = lane & 31;        // 32 lanes x 4ch = 128 = C
#pragma unroll
        for (int hp = 0; hp < H / 2; ++hp) {
            const int hd = hp * 2 + sub;
            const int c = lg * 4;
            const u16* rp = PLANAR ? (h + ((size_t)hd * NN + n) * C + c)
                                   : (h + (size_t)n * H * C + hd * C + c);
            uint2 q = *(const uint2*)rp;
            float4 s = *(const float4*)(att_s + hd * C + c);
            float4 dd = *(const float4*)(att_d + hd * C + c);
            float v0 = bflo(q.x), v1 = bfhi(q.x), v2 = bflo(q.y), v3 = bfhi(q.y);
            float ps = v0 * s.x + v1 * s.y + v2 * s.z + v3 * s.w;
            float pd = v0 * dd.x + v1 * dd.y + v2 * dd.z + v3 * dd.w;
#pragma unroll
            for (int off = 16; off; off >>= 1) {
                ps += __shfl_down(ps, off, 32);
                pd += __shfl_down(pd, off, 32);
            }
            if (lg == 0) {
                a_s[n * H + hd] = ps;
                a_d[n * H + hd] = pd;
            }
        }
    }
}

// ---------------- alpha: unnormalized exp (TRANSPOSED planes [H][ETOT]) + inv sums ----
template<int H>
__global__ __launch_bounds__(128)
void att_alpha3(const int* __restrict__ row_start, const int* __restrict__ slot_src,
                const float* __restrict__ a_s, const float* __restrict__ a_d,
                float* __restrict__ exal_t, float* __restrict__ inv) {
    const int d = blockIdx.x * 2 + (threadIdx.x >> 6);
    const int lane = threadIdx.x & 63;
    const int s0 = row_start[d], s1 = row_start[d + 1];
    float ad[H];
#pragma unroll
    for (int hd = 0; hd < H; ++hd) ad[hd] = a_d[(size_t)d * H + hd];
    float sums[H];
#pragma unroll
    for (int hd = 0; hd < H; ++hd) sums[hd] = 0.f;

    for (int base = s0; base < s1; base += 64) {
        int e = base + lane;
        bool ok = (e < s1);
        int src = ok ? slot_src[e] : 0;
        float as[H];
        if constexpr (H == 1) {
            as[0] = ok ? a_s[src] : 0.f;
        } else {
            const float2* asp = (const float2*)(a_s + (size_t)src * H);
#pragma unroll
            for (int i = 0; i < H / 2; ++i) {
                float2 q = ok ? asp[i] : make_float2(0.f, 0.f);
                as[2 * i] = q.x; as[2 * i + 1] = q.y;
            }
        }
#pragma unroll
        for (int hd = 0; hd < H; ++hd) {
            float t = as[hd] + ad[hd];
            t = (t > 0.f) ? t : 0.2f * t;          // leaky_relu 0.2
            float x = ok ? expf(t) : 0.f;          // logits small by construction
            sums[hd] += x;
            if (ok) exal_t[(size_t)hd * ETOT + e] = x;   // coalesced per plane
        }
    }
#pragma unroll
    for (int hd = 0; hd < H; ++hd) {
#pragma unroll
        for (int off = 32; off; off >>= 1) sums[hd] += __shfl_down(sums[hd], off);
    }
    if (lane == 0) {
#pragma unroll
        for (int hd = 0; hd < H; ++hd) inv[(size_t)d * H + hd] = 1.f / (sums[hd] + 1e-16f);
    }
}

// helper: accumulate 8 channels from a uint4 of packed bf16
__device__ __forceinline__ void fma8(float* acc, uint4 g, float a) {
    acc[0] += a * bflo(g.x); acc[1] += a * bfhi(g.x);
    acc[2] += a * bflo(g.y); acc[3] += a * bfhi(g.y);
    acc[4] += a * bflo(g.z); acc[5] += a * bfhi(g.z);
    acc[6] += a * bflo(g.w); acc[7] += a * bfhi(g.w);
}

// shared gather-accumulate body: one 16-lane group, one dst, 128 channels
template<int ACT>
__device__ __forceinline__ void scatter_body(
        int d, int cc, const int* __restrict__ row_start,
        const int* __restrict__ slot_src, const float* __restrict__ exp_pl,
        float sc_inv_sel, const u16* hb, int hstride,
        const float* __restrict__ bias, u16* __restrict__ out, int HC, int lg) {
    const int s0 = row_start[d], s1 = row_start[d + 1];
    float acc0[8] = {}, acc1[8] = {}, acc2[8] = {}, acc3[8] = {};
    for (int base = s0; base < s1; base += 16) {
        int e = base + lg;
        bool ok = (e < s1);
        int mySrc = 0; float mA = 0.f;
        if (ok) { mySrc = slot_src[e]; mA = exp_pl[e]; }
        int cnt = min(16, s1 - base);
        int j = 0;
        for (; j + 4 <= cnt; j += 4) {
            int sA = __shfl(mySrc, j, 16),     sB = __shfl(mySrc, j + 1, 16);
            int sC = __shfl(mySrc, j + 2, 16), sD = __shfl(mySrc, j + 3, 16);
            float aA = __shfl(mA, j, 16),     aB = __shfl(mA, j + 1, 16);
            float aC = __shfl(mA, j + 2, 16), aD = __shfl(mA, j + 3, 16);
            uint4 gA = *(const uint4*)(hb + (size_t)sA * hstride);
            uint4 gB = *(const uint4*)(hb + (size_t)sB * hstride);
            uint4 gC = *(const uint4*)(hb + (size_t)sC * hstride);
            uint4 gD = *(const uint4*)(hb + (size_t)sD * hstride);
            fma8(acc0, gA, aA); fma8(acc1, gB, aB);
            fma8(acc2, gC, aC); fma8(acc3, gD, aD);
        }
        for (; j < cnt; ++j) {
            int sA = __shfl(mySrc, j, 16);
            float aA = __shfl(mA, j, 16);
            uint4 gA = *(const uint4*)(hb + (size_t)sA * hstride);
            fma8(acc0, gA, aA);
        }
    }
    float4 b0 = *(const float4*)(bias + cc);
    float4 b1 = *(const float4*)(bias + cc + 4);
    float bb[8] = { b0.x, b0.y, b0.z, b0.w, b1.x, b1.y, b1.z, b1.w };
    u16 os[8];
#pragma unroll
    for (int k = 0; k < 8; ++k) {
        float v = (acc0[k] + acc1[k]) + (acc2[k] + acc3[k]);
        v = v * sc_inv_sel + bb[k];
        if (ACT == 1) v = (v > 0.f) ? v : (expf(v) - 1.f);   // elu
        else          v = fmaxf(v, 0.f);                      // relu
        os[k] = f2bf(v);
    }
    uint4 qo;
    qo.x = (u32)os[0] | ((u32)os[1] << 16);
    qo.y = (u32)os[2] | ((u32)os[3] << 16);
    qo.z = (u32)os[4] | ((u32)os[5] << 16);
    qo.w = (u32)os[6] | ((u32)os[7] << 16);
    *(uint4*)(out + (size_t)d * HC + cc) = qo;
}

// ---------------- scatter x1 (layer 1): XCD-affine planar ----------------
// 20 units = (plane 0..9) x (node-half). unit -> XCD unit%8 via bid%8 round-robin
// (perf heuristic only; correctness independent of placement). Each XCD's L2
// then holds ~one 2.56MB plane at a time instead of 3-4 (R8: FETCH 121MB).
// Grid: 15000 blocks (8 residues x 1875); blocks with unit>=20 exit.
__global__ __launch_bounds__(128)
void gat_scatter_x1(const int* __restrict__ row_start, const int* __restrict__ slot_src,
                    const float* __restrict__ exal_t, const float* __restrict__ inv,
                    const u16* __restrict__ h, const float* __restrict__ bias,
                    u16* __restrict__ out) {
    const int bid = blockIdx.x;
    const int k = bid & 7;
    const int t = bid >> 3;
    const int uidx = t / 625;
    const int loc  = t - uidx * 625;
    const int unit = k + 8 * uidx;
    if (unit >= 2 * H1) return;
    const int plane = unit >> 1;
    const int half  = unit & 1;
    const int grp = threadIdx.x >> 4;
    const int lg  = threadIdx.x & 15;
    const int d  = half * (NN / 2) + loc * 8 + grp;
    const int cc = plane * 128 + lg * 8;
    const float* exp_pl = exal_t + (size_t)plane * ETOT;
    const u16* hb = h + (size_t)plane * NN * 128 + lg * 8;
    scatter_body<1>(d, cc, row_start, slot_src, exp_pl,
                    inv[(size_t)d * H1 + plane], hb, 128, bias, out, HC1, lg);
}

// ---------------- scatter x2 (layer 2): XCD-affine channel slices ----------------
// slice = bid&7 -> XCD slice; each XCD's L2 holds exactly its 2.56MB column slice.
__global__ __launch_bounds__(128)
void gat_scatter_x2(const int* __restrict__ row_start, const int* __restrict__ slot_src,
                    const float* __restrict__ exal_t, const float* __restrict__ inv,
                    const u16* __restrict__ h, const float* __restrict__ bias,
                    u16* __restrict__ out) {
    const int bid = blockIdx.x;
    const int slice = bid & 7;
    const int chunk = bid >> 3;
    const int grp = threadIdx.x >> 4;
    const int lg  = threadIdx.x & 15;
    const int d  = chunk * 8 + grp;
    const int cc = slice * 128 + lg * 8;
    const u16* hb = h + cc;
    scatter_body<2>(d, cc, row_start, slot_src, exal_t,
                    inv[d], hb, HC2, bias, out, HC2, lg);
}

extern "C" void kernel_launch(void* const* d_in, const int* in_sizes, int n_in,
                              void* d_out, int out_size, void* d_ws, size_t ws_size,
                              hipStream_t stream) {
    const float* node      = (const float*)d_in[0];
    const int*   esrc      = (const int*)d_in[1];          // edge_index[0]
    const int*   edst      = ((const int*)d_in[1]) + EE;   // edge_index[1]
    const float* W1        = (const float*)d_in[2];
    const float* att_src1  = (const float*)d_in[3];
    const float* att_dst1  = (const float*)d_in[4];
    const float* b1        = (const float*)d_in[5];
    const float* W2        = (const float*)d_in[6];
    const float* att_src2  = (const float*)d_in[7];
    const float* att_dst2  = (const float*)d_in[8];
    const float* b2        = (const float*)d_in[9];
    const float* fc_w      = (const float*)d_in[10];
    const float* fc_b      = (const float*)d_in[11];
    float* out = (float*)d_out;

    // ---- workspace layout ----
    u16* bufA  = (u16*)d_ws;                        // [NN*HC1]  h1 planes, later h2
    u16* bufB  = bufA + (size_t)NN * HC1;           // [NN*HC1]  x2b, later out2b
    u16* nodeb = bufB + (size_t)NN * HC1;           // [NN*F_IN]
    u16* w1t   = nodeb + (size_t)NN * F_IN;         // [HC1*F_IN]
    u16* w2t   = w1t + (size_t)HC1 * F_IN;          // [HC2*HC1]
    u16* fcwt  = w2t + (size_t)HC2 * HC1;           // [OUT_DIM*OUT_DIM]
    float* exal  = (float*)(fcwt + (size_t)OUT_DIM * OUT_DIM);  // [H1*ETOT] planes
    float* inv   = exal + (size_t)ETOT * H1;        // [NN*H1]
    float* a_s1  = inv + (size_t)NN * H1;           // [NN*H1]
    float* a_d1  = a_s1 + (size_t)NN * H1;
    float* a_s2  = a_d1 + (size_t)NN * H1;          // [NN]
    float* a_d2  = a_s2 + NN;
    int* deg       = (int*)(a_d2 + NN);
    int* cursor    = deg + NN;
    int* row_start = cursor + NN;                   // [NN+1]
    int* slot_src  = row_start + NN + 8;            // [ETOT]

    // ---- conversions ----
    f32_to_bf16_kernel<<<(NN * F_IN + 255) / 256, 256, 0, stream>>>(node, nodeb, NN * F_IN);
    transpose_bf16_kernel<<<dim3(HC1 / 16, F_IN / 16), dim3(16, 16), 0, stream>>>(W1, w1t, F_IN, HC1);
    transpose_bf16_kernel<<<dim3(HC2 / 16, HC1 / 16), dim3(16, 16), 0, stream>>>(W2, w2t, HC1, HC2);
    transpose_bf16_kernel<<<dim3(OUT_DIM / 16, OUT_DIM / 16), dim3(16, 16), 0, stream>>>(fc_w, fcwt, OUT_DIM, OUT_DIM);

    // ---- CSR build ----
    hipMemsetAsync(deg, 0, 2 * NN * sizeof(int), stream);  // deg + cursor
    hist_kernel<<<(ETOT + 255) / 256, 256, 0, stream>>>(edst, deg);
    scan_kernel<<<1, 1024, 0, stream>>>(deg, row_start);
    fill_kernel<<<(ETOT + 255) / 256, 256, 0, stream>>>(esrc, edst, row_start, cursor, slot_src);

    // ---- layer 1 (h1 stored as head-major planes) ----
    gemm_bf16<0, 1><<<dim3(HC1 / 128, (NN + 127) / 128), 256, 0, stream>>>(nodeb, w1t, nullptr, bufA, NN, HC1, F_IN);
    att_logits3<H1, C1, true><<<NN / 2, 128, 0, stream>>>(bufA, att_src1, att_dst1, a_s1, a_d1);
    att_alpha3<H1><<<NN / 2, 128, 0, stream>>>(row_start, slot_src, a_s1, a_d1, exal, inv);
    gat_scatter_x1<<<15000, 128, 0, stream>>>(row_start, slot_src, exal, inv, bufA, b1, bufB);

    // ---- layer 2 (node-major, XCD-affine channel slices) ----
    gemm_bf16<0, 0><<<dim3(HC2 / 128, (NN + 127) / 128), 256, 0, stream>>>(bufB, w2t, nullptr, bufA, NN, HC2, HC1);
    att_logits3<H2, C2, false><<<NN / 2, 128, 0, stream>>>(bufA, att_src2, att_dst2, a_s2, a_d2);
    att_alpha3<H2><<<NN / 2, 128, 0, stream>>>(row_start, slot_src, a_s2, a_d2, exal, inv);
    gat_scatter_x2<<<10000, 128, 0, stream>>>(row_start, slot_src, exal, inv, bufA, b2, bufB);

    // ---- fc: out = relu(out2 @ fc_w + fc_b), f32 out ----
    gemm_bf16<1, 0><<<dim3(OUT_DIM / 128, (NN + 127) / 128), 256, 0, stream>>>(bufB, fcwt, fc_b, out, NN, OUT_DIM, OUT_DIM);
}

// Round 15
// 231.564 us; speedup vs baseline: 1.1496x; 1.0135x over previous
//
#include <hip/hip_runtime.h>
#include <hip/hip_bf16.h>
#include <cstddef>
#include <cstdint>

// Problem constants
#define NN 10000
#define EE 160000
#define ETOT (EE + NN)
#define F_IN 128
#define H1 10
#define C1 128
#define HC1 1280
#define H2 1
#define C2 1024
#define HC2 1024
#define OUT_DIM 1024

typedef __attribute__((ext_vector_type(4))) float f32x4;
typedef __attribute__((ext_vector_type(8))) _Float16 h16x8;
typedef __attribute__((ext_vector_type(2))) _Float16 h16x2;
typedef unsigned int u32;
typedef unsigned short u16;

#if defined(__has_builtin)
# if __has_builtin(__builtin_amdgcn_fdot2) && __has_builtin(__builtin_amdgcn_perm)
#  define USE_FDOT2 1
# endif
#endif

__device__ __forceinline__ float h2f(u16 v) {
    union { u16 u; _Float16 h; } x; x.u = v; return (float)x.h;
}
__device__ __forceinline__ u16 f2h(float f) {
    union { u16 u; _Float16 h; } x; x.h = (_Float16)f; return x.u;
}
__device__ __forceinline__ float hlo(u32 q) {   // low fp16 of a packed u32
    union { u32 u; _Float16 h[2]; } x; x.u = q; return (float)x.h[0];
}
__device__ __forceinline__ float hhi(u32 q) {   // high fp16 of a packed u32
    union { u32 u; _Float16 h[2]; } x; x.u = q; return (float)x.h[1];
}
__device__ __forceinline__ h16x2 as_h2(u32 q) {
    union { u32 u; h16x2 v; } x; x.u = q; return x.v;
}
// cvt_pkrtz returns __fp16 ext_vector(2); bit-cast to our _Float16 vector type.
__device__ __forceinline__ h16x2 pk2h(float a, float b) {
    auto t = __builtin_amdgcn_cvt_pkrtz(a, b);
    union { decltype(t) i; h16x2 o; } u; u.i = t; return u.o;
}

__device__ __forceinline__ void gld16(const void* g, void* l) {
    __builtin_amdgcn_global_load_lds((const __attribute__((address_space(1))) u32*)g,
                                     (__attribute__((address_space(3))) u32*)l, 16, 0, 0);
}

// Producer-side drain of async global_load_lds BEFORE the barrier (round-6 race fix).
__device__ __forceinline__ void vm_drain() {
    asm volatile("s_waitcnt vmcnt(0)" ::: "memory");
}

// ---------------- conversions ----------------
__global__ void f32_to_f16_kernel(const float* __restrict__ in, u16* __restrict__ out, int n) {
    int i = blockIdx.x * 256 + threadIdx.x;
    if (i < n) out[i] = f2h(in[i]);
}

// in: [K][N] row-major f32; out: [N][K] fp16.
__global__ void transpose_f16_kernel(const float* __restrict__ in, u16* __restrict__ out,
                                     int K, int N) {
    __shared__ u16 t[16][17];
    int n0 = blockIdx.x * 16, k0 = blockIdx.y * 16;
    t[threadIdx.y][threadIdx.x] = f2h(in[(size_t)(k0 + threadIdx.y) * N + n0 + threadIdx.x]);
    __syncthreads();
    out[(size_t)(n0 + threadIdx.y) * K + k0 + threadIdx.x] = t[threadIdx.x][threadIdx.y];
}

// ---------------- CSR build ----------------
__global__ void hist_kernel(const int* __restrict__ edst, int* __restrict__ deg) {
    int e = blockIdx.x * 256 + threadIdx.x;
    if (e >= ETOT) return;
    int d = (e < EE) ? edst[e] : (e - EE);
    atomicAdd(&deg[d], 1);
}

// shfl-based single-block scan (1024 threads)
__global__ void scan_kernel(const int* __restrict__ deg, int* __restrict__ row_start) {
    __shared__ int wsum[16];
    const int tid = threadIdx.x;
    const int lane = tid & 63;
    const int wid = tid >> 6;
    int carry = 0;
    for (int base = 0; base < NN; base += 1024) {
        int i = base + tid;
        int v = (i < NN) ? deg[i] : 0;
        int x = v;
#pragma unroll
        for (int o = 1; o < 64; o <<= 1) {
            int t = __shfl_up(x, o);
            if (lane >= o) x += t;
        }
        if (lane == 63) wsum[wid] = x;
        __syncthreads();
        if (wid == 0) {
            int w = (lane < 16) ? wsum[lane] : 0;
#pragma unroll
            for (int o = 1; o < 16; o <<= 1) {
                int t = __shfl_up(w, o);
                if (lane >= o) w += t;
            }
            if (lane < 16) wsum[lane] = w;
        }
        __syncthreads();
        int woff = (wid == 0) ? 0 : wsum[wid - 1];
        if (i < NN) row_start[i] = carry + woff + x - v;   // exclusive
        carry += wsum[15];
        __syncthreads();
    }
    if (tid == 0) row_start[NN] = carry;
}

__global__ void fill_kernel(const int* __restrict__ esrc, const int* __restrict__ edst,
                            const int* __restrict__ row_start, int* __restrict__ cursor,
                            int* __restrict__ slot_src) {
    int e = blockIdx.x * 256 + threadIdx.x;
    if (e >= ETOT) return;
    int s, d;
    if (e < EE) { s = esrc[e]; d = edst[e]; }
    else        { s = d = e - EE; }
    int pos = atomicAdd(&cursor[d], 1);
    slot_src[row_start[d] + pos] = s;
}

// ---------------- fp16 MFMA GEMM: C = A[MxK] * Bt[NxK]^T ----------------
// R8 config (best measured): 128x128 tile, 4 waves (2x2), 16x16x32 MFMA, BK=32,
// double-buffered LDS prefetch + explicit producer vmcnt drain, bijective XCD
// swizzle. fp16 operands (same fragment/CD layout as bf16 — dtype-independent).
// BIAS_RELU==1: +bias, relu, f32 out. HEADMAJ==1: fp16 head-major planes
// [n/128][M][128].
template<int BIAS_RELU, int HEADMAJ>
__global__ __launch_bounds__(256, 2)
void gemm_f16(const u16* __restrict__ A, const u16* __restrict__ Bt,
              const float* __restrict__ bias, void* __restrict__ Cout,
              int M, int N, int K) {
    __shared__ u16 Als[2][128 * 32];
    __shared__ u16 Bls[2][128 * 32];
    const int tid  = threadIdx.x;
    const int wave = tid >> 6;
    const int lane = tid & 63;

    // bijective XCD swizzle
    const int nwg = gridDim.x * gridDim.y;
    const int bid = blockIdx.y * gridDim.x + blockIdx.x;
    const int q = nwg >> 3, r = nwg & 7;
    const int xcd = bid & 7, idx = bid >> 3;
    const int swz = (xcd < r ? xcd * (q + 1) : r * (q + 1) + (xcd - r) * q) + idx;
    const int bm = (swz / gridDim.x) * 128;
    const int bn = (swz % gridDim.x) * 128;

    const int wr = wave >> 1, wc = wave & 1;   // 2x2 waves, each 64x64
    const int lr = lane & 15;
    const int kc = lane >> 4;

    f32x4 acc[4][4] = {};

    const int srow = tid >> 2;
    const int scol = (tid & 3) * 8;
    int arow0 = bm + srow;       if (arow0 >= M) arow0 = M - 1;
    int arow1 = bm + 64 + srow;  if (arow1 >= M) arow1 = M - 1;
    const int brow0 = bn + srow;
    const int brow1 = bn + 64 + srow;

    const u16* aP0 = A  + (size_t)arow0 * K + scol;
    const u16* aP1 = A  + (size_t)arow1 * K + scol;
    const u16* bP0 = Bt + (size_t)brow0 * K + scol;
    const u16* bP1 = Bt + (size_t)brow1 * K + scol;

    // prologue: stage tile 0 into buf 0
    gld16(aP0, &Als[0][(size_t)wave * 512]);
    gld16(aP1, &Als[0][2048 + (size_t)wave * 512]);
    gld16(bP0, &Bls[0][(size_t)wave * 512]);
    gld16(bP1, &Bls[0][2048 + (size_t)wave * 512]);
    vm_drain();
    __syncthreads();

    int cur = 0;
    for (int k0 = 0; k0 < K; k0 += 32) {
        if (k0 + 32 < K) {
            int nxt = cur ^ 1;
            gld16(aP0 + k0 + 32, &Als[nxt][(size_t)wave * 512]);
            gld16(aP1 + k0 + 32, &Als[nxt][2048 + (size_t)wave * 512]);
            gld16(bP0 + k0 + 32, &Bls[nxt][(size_t)wave * 512]);
            gld16(bP1 + k0 + 32, &Bls[nxt][2048 + (size_t)wave * 512]);
        }

        h16x8 af[4], bg[4];
#pragma unroll
        for (int i = 0; i < 4; ++i)
            af[i] = *(const h16x8*)&Als[cur][(wr * 64 + i * 16 + lr) * 32 + kc * 8];
#pragma unroll
        for (int j = 0; j < 4; ++j)
            bg[j] = *(const h16x8*)&Bls[cur][(wc * 64 + j * 16 + lr) * 32 + kc * 8];
#pragma unroll
        for (int i = 0; i < 4; ++i)
#pragma unroll
            for (int j = 0; j < 4; ++j)
                acc[i][j] = __builtin_amdgcn_mfma_f32_16x16x32_f16(af[i], bg[j], acc[i][j], 0, 0, 0);

        vm_drain();      // prefetch visible to ALL waves before the barrier
        __syncthreads();
        cur ^= 1;
    }

    // C/D layout: col = lane&15, row = (lane>>4)*4 + reg
#pragma unroll
    for (int i = 0; i < 4; ++i) {
#pragma unroll
        for (int r2 = 0; r2 < 4; ++r2) {
            int m = bm + wr * 64 + i * 16 + kc * 4 + r2;
            if (m >= M) continue;
#pragma unroll
            for (int j = 0; j < 4; ++j) {
                int n = bn + wc * 64 + j * 16 + lr;
                float v = acc[i][j][r2];
                if (BIAS_RELU) {
                    v += bias[n];
                    v = fmaxf(v, 0.f);
                    ((float*)Cout)[(size_t)m * N + n] = v;
                } else if (HEADMAJ) {
                    ((u16*)Cout)[(size_t)(n >> 7) * NN * 128 + (size_t)m * 128 + (n & 127)] = f2h(v);
                } else {
                    ((u16*)Cout)[(size_t)m * N + n] = f2h(v);
                }
            }
        }
    }
}

// ---------------- logits: 4 ch/lane vector loads ----------------
// PLANAR: h stored as [head][NN][C] planes. H even: half-wave per head pair member.
template<int H, int C, bool PLANAR>
__global__ __launch_bounds__(128)
void att_logits3(const u16* __restrict__ h, const float* __restrict__ att_s,
                 const float* __restrict__ att_d, float* __restrict__ a_s,
                 float* __restrict__ a_d) {
    const int n = blockIdx.x * 2 + (threadIdx.x >> 6);
    const int lane = threadIdx.x & 63;
    if constexpr (H == 1) {
        const u16* row = h + (size_t)n * C;
        float ps = 0.f, pd = 0.f;
        for (int c = lane * 4; c < C; c += 256) {
            uint2 q = *(const uint2*)(row + c);
            float4 s = *(const float4*)(att_s + c);
            float4 dd = *(const float4*)(att_d + c);
            float v0 = hlo(q.x), v1 = hhi(q.x), v2 = hlo(q.y), v3 = hhi(q.y);
            ps += v0 * s.x + v1 * s.y + v2 * s.z + v3 * s.w;
            pd += v0 * dd.x + v1 * dd.y + v2 * dd.z + v3 * dd.w;
        }
#pragma unroll
        for (int off = 32; off; off >>= 1) {
            ps += __shfl_down(ps, off);
            pd += __shfl_down(pd, off);
        }
        if (lane == 0) { a_s[n] = ps; a_d[n] = pd; }
    } else {
        const int sub = lane >> 5;        // which head of the pair
        const int lg  = lane & 31;        // 32 lanes x 4ch = 128 = C
#pragma unroll
        for (int hp = 0; hp < H / 2; ++hp) {
            const int hd = hp * 2 + sub;
            const int c = lg * 4;
            const u16* rp = PLANAR ? (h + ((size_t)hd * NN + n) * C + c)
                                   : (h + (size_t)n * H * C + hd * C + c);
            uint2 q = *(const uint2*)rp;
            float4 s = *(const float4*)(att_s + hd * C + c);
            float4 dd = *(const float4*)(att_d + hd * C + c);
            float v0 = hlo(q.x), v1 = hhi(q.x), v2 = hlo(q.y), v3 = hhi(q.y);
            float ps = v0 * s.x + v1 * s.y + v2 * s.z + v3 * s.w;
            float pd = v0 * dd.x + v1 * dd.y + v2 * dd.z + v3 * dd.w;
#pragma unroll
            for (int off = 16; off; off >>= 1) {
                ps += __shfl_down(ps, off, 32);
                pd += __shfl_down(pd, off, 32);
            }
            if (lg == 0) {
                a_s[n * H + hd] = ps;
                a_d[n * H + hd] = pd;
            }
        }
    }
}

// ---------------- alpha: unnormalized exp (TRANSPOSED planes [H][ETOT]) + inv sums ----
template<int H>
__global__ __launch_bounds__(128)
void att_alpha3(const int* __restrict__ row_start, const int* __restrict__ slot_src,
                const float* __restrict__ a_s, const float* __restrict__ a_d,
                float* __restrict__ exal_t, float* __restrict__ inv) {
    const int d = blockIdx.x * 2 + (threadIdx.x >> 6);
    const int lane = threadIdx.x & 63;
    const int s0 = row_start[d], s1 = row_start[d + 1];
    float ad[H];
#pragma unroll
    for (int hd = 0; hd < H; ++hd) ad[hd] = a_d[(size_t)d * H + hd];
    float sums[H];
#pragma unroll
    for (int hd = 0; hd < H; ++hd) sums[hd] = 0.f;

    for (int base = s0; base < s1; base += 64) {
        int e = base + lane;
        bool ok = (e < s1);
        int src = ok ? slot_src[e] : 0;
        float as[H];
        if constexpr (H == 1) {
            as[0] = ok ? a_s[src] : 0.f;
        } else {
            const float2* asp = (const float2*)(a_s + (size_t)src * H);
#pragma unroll
            for (int i = 0; i < H / 2; ++i) {
                float2 q = ok ? asp[i] : make_float2(0.f, 0.f);
                as[2 * i] = q.x; as[2 * i + 1] = q.y;
            }
        }
#pragma unroll
        for (int hd = 0; hd < H; ++hd) {
            float t = as[hd] + ad[hd];
            t = (t > 0.f) ? t : 0.2f * t;          // leaky_relu 0.2
            float x = ok ? expf(t) : 0.f;          // logits small by construction
            sums[hd] += x;
            if (ok) exal_t[(size_t)hd * ETOT + e] = x;   // coalesced per plane
        }
    }
#pragma unroll
    for (int hd = 0; hd < H; ++hd) {
#pragma unroll
        for (int off = 32; off; off >>= 1) sums[hd] += __shfl_down(sums[hd], off);
    }
    if (lane == 0) {
#pragma unroll
        for (int hd = 0; hd < H; ++hd) inv[(size_t)d * H + hd] = 1.f / (sums[hd] + 1e-16f);
    }
}

// helper: accumulate 8 fp16 channels from a uint4 (scalar fallback)
__device__ __forceinline__ void fma8h(float* acc, uint4 g, float a) {
    acc[0] += a * hlo(g.x); acc[1] += a * hhi(g.x);
    acc[2] += a * hlo(g.y); acc[3] += a * hhi(g.y);
    acc[4] += a * hlo(g.z); acc[5] += a * hhi(g.z);
    acc[6] += a * hlo(g.w); acc[7] += a * hhi(g.w);
}

#ifdef USE_FDOT2
// paired-edge accumulate: acc[c] += aA*hA[c] + aB*hB[c] via v_perm + v_dot2_f32_f16
// ap = (aA, aB) packed fp16. ~1 VALU per channel-edge (vs 2 for unpack+fma).
__device__ __forceinline__ void dot8h(float* acc, uint4 gA, uint4 gB, h16x2 ap) {
    u32 p;
    p = __builtin_amdgcn_perm(gB.x, gA.x, 0x05040100u);
    acc[0] = __builtin_amdgcn_fdot2(as_h2(p), ap, acc[0], false);
    p = __builtin_amdgcn_perm(gB.x, gA.x, 0x07060302u);
    acc[1] = __builtin_amdgcn_fdot2(as_h2(p), ap, acc[1], false);
    p = __builtin_amdgcn_perm(gB.y, gA.y, 0x05040100u);
    acc[2] = __builtin_amdgcn_fdot2(as_h2(p), ap, acc[2], false);
    p = __builtin_amdgcn_perm(gB.y, gA.y, 0x07060302u);
    acc[3] = __builtin_amdgcn_fdot2(as_h2(p), ap, acc[3], false);
    p = __builtin_amdgcn_perm(gB.z, gA.z, 0x05040100u);
    acc[4] = __builtin_amdgcn_fdot2(as_h2(p), ap, acc[4], false);
    p = __builtin_amdgcn_perm(gB.z, gA.z, 0x07060302u);
    acc[5] = __builtin_amdgcn_fdot2(as_h2(p), ap, acc[5], false);
    p = __builtin_amdgcn_perm(gB.w, gA.w, 0x05040100u);
    acc[6] = __builtin_amdgcn_fdot2(as_h2(p), ap, acc[6], false);
    p = __builtin_amdgcn_perm(gB.w, gA.w, 0x07060302u);
    acc[7] = __builtin_amdgcn_fdot2(as_h2(p), ap, acc[7], false);
}
#endif

// shared gather-accumulate body: one 16-lane group, one dst, 128 channels
template<int ACT>
__device__ __forceinline__ void scatter_body(
        int d, int cc, const int* __restrict__ row_start,
        const int* __restrict__ slot_src, const float* __restrict__ exp_pl,
        float sc_inv_sel, const u16* hb, int hstride,
        const float* __restrict__ bias, u16* __restrict__ out, int HC, int lg) {
    const int s0 = row_start[d], s1 = row_start[d + 1];
    float acc0[8] = {}, acc1[8] = {};
    for (int base = s0; base < s1; base += 16) {
        int e = base + lg;
        bool ok = (e < s1);
        int mySrc = 0; float mA = 0.f;
        if (ok) { mySrc = slot_src[e]; mA = exp_pl[e]; }
        int cnt = min(16, s1 - base);
        int j = 0;
#ifdef USE_FDOT2
        for (; j + 4 <= cnt; j += 4) {
            int sA = __shfl(mySrc, j, 16),     sB = __shfl(mySrc, j + 1, 16);
            int sC = __shfl(mySrc, j + 2, 16), sD = __shfl(mySrc, j + 3, 16);
            float aA = __shfl(mA, j, 16),     aB = __shfl(mA, j + 1, 16);
            float aC = __shfl(mA, j + 2, 16), aD = __shfl(mA, j + 3, 16);
            h16x2 apAB = pk2h(aA, aB);
            h16x2 apCD = pk2h(aC, aD);
            uint4 gA = *(const uint4*)(hb + (size_t)sA * hstride);
            uint4 gB = *(const uint4*)(hb + (size_t)sB * hstride);
            uint4 gC = *(const uint4*)(hb + (size_t)sC * hstride);
            uint4 gD = *(const uint4*)(hb + (size_t)sD * hstride);
            dot8h(acc0, gA, gB, apAB);
            dot8h(acc1, gC, gD, apCD);
        }
        for (; j < cnt; ++j) {
            int sA = __shfl(mySrc, j, 16);
            float aA = __shfl(mA, j, 16);
            uint4 gA = *(const uint4*)(hb + (size_t)sA * hstride);
            fma8h(acc0, gA, aA);
        }
#else
        for (; j + 2 <= cnt; j += 2) {
            int sA = __shfl(mySrc, j, 16),     sB = __shfl(mySrc, j + 1, 16);
            float aA = __shfl(mA, j, 16),     aB = __shfl(mA, j + 1, 16);
            uint4 gA = *(const uint4*)(hb + (size_t)sA * hstride);
            uint4 gB = *(const uint4*)(hb + (size_t)sB * hstride);
            fma8h(acc0, gA, aA);
            fma8h(acc1, gB, aB);
        }
        for (; j < cnt; ++j) {
            int sA = __shfl(mySrc, j, 16);
            float aA = __shfl(mA, j, 16);
            uint4 gA = *(const uint4*)(hb + (size_t)sA * hstride);
            fma8h(acc0, gA, aA);
        }
#endif
    }
    float4 b0 = *(const float4*)(bias + cc);
    float4 b1 = *(const float4*)(bias + cc + 4);
    float bb[8] = { b0.x, b0.y, b0.z, b0.w, b1.x, b1.y, b1.z, b1.w };
    u16 os[8];
#pragma unroll
    for (int k = 0; k < 8; ++k) {
        float v = acc0[k] + acc1[k];
        v = v * sc_inv_sel + bb[k];
        if (ACT == 1) v = (v > 0.f) ? v : (expf(v) - 1.f);   // elu
        else          v = fmaxf(v, 0.f);                      // relu
        os[k] = f2h(v);
    }
    uint4 qo;
    qo.x = (u32)os[0] | ((u32)os[1] << 16);
    qo.y = (u32)os[2] | ((u32)os[3] << 16);
    qo.z = (u32)os[4] | ((u32)os[5] << 16);
    qo.w = (u32)os[6] | ((u32)os[7] << 16);
    *(uint4*)(out + (size_t)d * HC + cc) = qo;
}

// ---------------- scatter x1 (layer 1): XCD-affine planar ----------------
// 20 units = (plane 0..9) x (node-half); unit -> XCD unit%8 via bid%8 round-robin
// (perf heuristic only). Each XCD's L2 holds ~one 2.56MB plane (R13: FETCH
// 121->38MB). Grid: 15000 blocks; blocks with unit>=20 exit.
__global__ __launch_bounds__(128)
void gat_scatter_x1(const int* __restrict__ row_start, const int* __restrict__ slot_src,
                    const float* __restrict__ exal_t, const float* __restrict__ inv,
                    const u16* __restrict__ h, const float* __restrict__ bias,
                    u16* __restrict__ out) {
    const int bid = blockIdx.x;
    const int k = bid & 7;
    const int t = bid >> 3;
    const int uidx = t / 625;
    const int loc  = t - uidx * 625;
    const int unit = k + 8 * uidx;
    if (unit >= 2 * H1) return;
    const int plane = unit >> 1;
    const int half  = unit & 1;
    const int grp = threadIdx.x >> 4;
    const int lg  = threadIdx.x & 15;
    const int d  = half * (NN / 2) + loc * 8 + grp;
    const int cc = plane * 128 + lg * 8;
    const float* exp_pl = exal_t + (size_t)plane * ETOT;
    const u16* hb = h + (size_t)plane * NN * 128 + lg * 8;
    scatter_body<1>(d, cc, row_start, slot_src, exp_pl,
                    inv[(size_t)d * H1 + plane], hb, 128, bias, out, HC1, lg);
}

// ---------------- scatter x2 (layer 2): XCD-affine channel slices ----------------
__global__ __launch_bounds__(128)
void gat_scatter_x2(const int* __restrict__ row_start, const int* __restrict__ slot_src,
                    const float* __restrict__ exal_t, const float* __restrict__ inv,
                    const u16* __restrict__ h, const float* __restrict__ bias,
                    u16* __restrict__ out) {
    const int bid = blockIdx.x;
    const int slice = bid & 7;
    const int chunk = bid >> 3;
    const int grp = threadIdx.x >> 4;
    const int lg  = threadIdx.x & 15;
    const int d  = chunk * 8 + grp;
    const int cc = slice * 128 + lg * 8;
    const u16* hb = h + cc;
    scatter_body<2>(d, cc, row_start, slot_src, exal_t,
                    inv[d], hb, HC2, bias, out, HC2, lg);
}

extern "C" void kernel_launch(void* const* d_in, const int* in_sizes, int n_in,
                              void* d_out, int out_size, void* d_ws, size_t ws_size,
                              hipStream_t stream) {
    const float* node      = (const float*)d_in[0];
    const int*   esrc      = (const int*)d_in[1];          // edge_index[0]
    const int*   edst      = ((const int*)d_in[1]) + EE;   // edge_index[1]
    const float* W1        = (const float*)d_in[2];
    const float* att_src1  = (const float*)d_in[3];
    const float* att_dst1  = (const float*)d_in[4];
    const float* b1        = (const float*)d_in[5];
    const float* W2        = (const float*)d_in[6];
    const float* att_src2  = (const float*)d_in[7];
    const float* att_dst2  = (const float*)d_in[8];
    const float* b2        = (const float*)d_in[9];
    const float* fc_w      = (const float*)d_in[10];
    const float* fc_b      = (const float*)d_in[11];
    float* out = (float*)d_out;

    // ---- workspace layout ----
    u16* bufA  = (u16*)d_ws;                        // [NN*HC1]  h1 planes, later h2
    u16* bufB  = bufA + (size_t)NN * HC1;           // [NN*HC1]  x2, later out2
    u16* nodeb = bufB + (size_t)NN * HC1;           // [NN*F_IN]
    u16* w1t   = nodeb + (size_t)NN * F_IN;         // [HC1*F_IN]
    u16* w2t   = w1t + (size_t)HC1 * F_IN;          // [HC2*HC1]
    u16* fcwt  = w2t + (size_t)HC2 * HC1;           // [OUT_DIM*OUT_DIM]
    float* exal  = (float*)(fcwt + (size_t)OUT_DIM * OUT_DIM);  // [H1*ETOT] planes
    float* inv   = exal + (size_t)ETOT * H1;        // [NN*H1]
    float* a_s1  = inv + (size_t)NN * H1;           // [NN*H1]
    float* a_d1  = a_s1 + (size_t)NN * H1;
    float* a_s2  = a_d1 + (size_t)NN * H1;          // [NN]
    float* a_d2  = a_s2 + NN;
    int* deg       = (int*)(a_d2 + NN);
    int* cursor    = deg + NN;
    int* row_start = cursor + NN;                   // [NN+1]
    int* slot_src  = row_start + NN + 8;            // [ETOT]

    // ---- conversions ----
    f32_to_f16_kernel<<<(NN * F_IN + 255) / 256, 256, 0, stream>>>(node, nodeb, NN * F_IN);
    transpose_f16_kernel<<<dim3(HC1 / 16, F_IN / 16), dim3(16, 16), 0, stream>>>(W1, w1t, F_IN, HC1);
    transpose_f16_kernel<<<dim3(HC2 / 16, HC1 / 16), dim3(16, 16), 0, stream>>>(W2, w2t, HC1, HC2);
    transpose_f16_kernel<<<dim3(OUT_DIM / 16, OUT_DIM / 16), dim3(16, 16), 0, stream>>>(fc_w, fcwt, OUT_DIM, OUT_DIM);

    // ---- CSR build ----
    hipMemsetAsync(deg, 0, 2 * NN * sizeof(int), stream);  // deg + cursor
    hist_kernel<<<(ETOT + 255) / 256, 256, 0, stream>>>(edst, deg);
    scan_kernel<<<1, 1024, 0, stream>>>(deg, row_start);
    fill_kernel<<<(ETOT + 255) / 256, 256, 0, stream>>>(esrc, edst, row_start, cursor, slot_src);

    // ---- layer 1 (h1 stored as head-major planes) ----
    gemm_f16<0, 1><<<dim3(HC1 / 128, (NN + 127) / 128), 256, 0, stream>>>(nodeb, w1t, nullptr, bufA, NN, HC1, F_IN);
    att_logits3<H1, C1, true><<<NN / 2, 128, 0, stream>>>(bufA, att_src1, att_dst1, a_s1, a_d1);
    att_alpha3<H1><<<NN / 2, 128, 0, stream>>>(row_start, slot_src, a_s1, a_d1, exal, inv);
    gat_scatter_x1<<<15000, 128, 0, stream>>>(row_start, slot_src, exal, inv, bufA, b1, bufB);

    // ---- layer 2 (node-major, XCD-affine channel slices) ----
    gemm_f16<0, 0><<<dim3(HC2 / 128, (NN + 127) / 128), 256, 0, stream>>>(bufB, w2t, nullptr, bufA, NN, HC2, HC1);
    att_logits3<H2, C2, false><<<NN / 2, 128, 0, stream>>>(bufA, att_src2, att_dst2, a_s2, a_d2);
    att_alpha3<H2><<<NN / 2, 128, 0, stream>>>(row_start, slot_src, a_s2, a_d2, exal, inv);
    gat_scatter_x2<<<10000, 128, 0, stream>>>(row_start, slot_src, exal, inv, bufA, b2, bufB);

    // ---- fc: out = relu(out2 @ fc_w + fc_b), f32 out ----
    gemm_f16<1, 0><<<dim3(OUT_DIM / 128, (NN + 127) / 128), 256, 0, stream>>>(bufB, fcwt, fc_b, out, NN, OUT_DIM, OUT_DIM);
}

// Round 16
// 224.629 us; speedup vs baseline: 1.1851x; 1.0309x over previous
//
#include <hip/hip_runtime.h>
#include <hip/hip_bf16.h>
#include <cstddef>
#include <cstdint>

// Problem constants
#define NN 10000
#define EE 160000
#define ETOT (EE + NN)
#define F_IN 128
#define H1 10
#define C1 128
#define HC1 1280
#define H2 1
#define C2 1024
#define HC2 1024
#define OUT_DIM 1024

typedef __attribute__((ext_vector_type(4))) float f32x4;
typedef __attribute__((ext_vector_type(8))) _Float16 h16x8;
typedef __attribute__((ext_vector_type(2))) _Float16 h16x2;
typedef unsigned int u32;
typedef unsigned short u16;

#if defined(__has_builtin)
# if __has_builtin(__builtin_amdgcn_fdot2) && __has_builtin(__builtin_amdgcn_perm)
#  define USE_FDOT2 1
# endif
#endif

__device__ __forceinline__ float h2f(u16 v) {
    union { u16 u; _Float16 h; } x; x.u = v; return (float)x.h;
}
__device__ __forceinline__ u16 f2h(float f) {
    union { u16 u; _Float16 h; } x; x.h = (_Float16)f; return x.u;
}
__device__ __forceinline__ float hlo(u32 q) {   // low fp16 of a packed u32
    union { u32 u; _Float16 h[2]; } x; x.u = q; return (float)x.h[0];
}
__device__ __forceinline__ float hhi(u32 q) {   // high fp16 of a packed u32
    union { u32 u; _Float16 h[2]; } x; x.u = q; return (float)x.h[1];
}
__device__ __forceinline__ h16x2 as_h2(u32 q) {
    union { u32 u; h16x2 v; } x; x.u = q; return x.v;
}
// cvt_pkrtz returns __fp16 ext_vector(2); bit-cast to our _Float16 vector type.
__device__ __forceinline__ h16x2 pk2h(float a, float b) {
    auto t = __builtin_amdgcn_cvt_pkrtz(a, b);
    union { decltype(t) i; h16x2 o; } u; u.i = t; return u.o;
}

__device__ __forceinline__ void gld16(const void* g, void* l) {
    __builtin_amdgcn_global_load_lds((const __attribute__((address_space(1))) u32*)g,
                                     (__attribute__((address_space(3))) u32*)l, 16, 0, 0);
}

// Producer-side drain of async global_load_lds BEFORE the barrier (round-6 race fix).
__device__ __forceinline__ void vm_drain() {
    asm volatile("s_waitcnt vmcnt(0)" ::: "memory");
}

// ---------------- fused prep: 3 weight transposes + node f32->f16 + edge hist ----
// One launch replaces 5. Each block takes exactly ONE branch (uniform within the
// block), so the transpose's __syncthreads is safe. All branches: independent
// reads of inputs, disjoint writes.
#define W1T_BLKS  (80 * 8)     // (HC1/16) x (F_IN/16)
#define W2T_BLKS  (64 * 80)    // (HC2/16) x (HC1/16)
#define FCT_BLKS  (64 * 64)    // (OUT/16) x (OUT/16)
#define NODE_BLKS 1250         // NN*F_IN / (256*4)
#define HIST_BLKS 665          // ceil(ETOT/256)
#define PREP_BLKS (W1T_BLKS + W2T_BLKS + FCT_BLKS + NODE_BLKS + HIST_BLKS)

__device__ __forceinline__ void transpose_tile16(const float* __restrict__ in,
                                                 u16* __restrict__ out,
                                                 int K, int N, int bx, int by,
                                                 u16 (*t)[17]) {
    const int tx = threadIdx.x & 15, ty = threadIdx.x >> 4;
    int n0 = bx * 16, k0 = by * 16;
    t[ty][tx] = f2h(in[(size_t)(k0 + ty) * N + n0 + tx]);
    __syncthreads();
    out[(size_t)(n0 + ty) * K + k0 + tx] = t[tx][ty];
}

__global__ __launch_bounds__(256)
void prep_kernel(const float* __restrict__ node, u16* __restrict__ nodeb,
                 const float* __restrict__ W1, u16* __restrict__ w1t,
                 const float* __restrict__ W2, u16* __restrict__ w2t,
                 const float* __restrict__ fcw, u16* __restrict__ fcwt,
                 const int* __restrict__ edst, int* __restrict__ deg) {
    __shared__ u16 t[16][17];
    int b = blockIdx.x;
    if (b < W1T_BLKS) {
        transpose_tile16(W1, w1t, F_IN, HC1, b % 80, b / 80, t);
        return;
    }
    b -= W1T_BLKS;
    if (b < W2T_BLKS) {
        transpose_tile16(W2, w2t, HC1, HC2, b % 64, b / 64, t);
        return;
    }
    b -= W2T_BLKS;
    if (b < FCT_BLKS) {
        transpose_tile16(fcw, fcwt, OUT_DIM, OUT_DIM, b % 64, b / 64, t);
        return;
    }
    b -= FCT_BLKS;
    if (b < NODE_BLKS) {
        int i = (b * 256 + threadIdx.x) * 4;          // NN*F_IN = 1,280,000 exact
        float4 v = *(const float4*)(node + i);
        ushort4 o;
        o.x = f2h(v.x); o.y = f2h(v.y); o.z = f2h(v.z); o.w = f2h(v.w);
        *(ushort4*)(nodeb + i) = o;
        return;
    }
    b -= NODE_BLKS;
    int e = b * 256 + threadIdx.x;
    if (e < ETOT) {
        int d = (e < EE) ? edst[e] : (e - EE);
        atomicAdd(&deg[d], 1);
    }
}

// ---------------- CSR build (scan + fill) ----------------
// shfl-based single-block scan (1024 threads)
__global__ void scan_kernel(const int* __restrict__ deg, int* __restrict__ row_start) {
    __shared__ int wsum[16];
    const int tid = threadIdx.x;
    const int lane = tid & 63;
    const int wid = tid >> 6;
    int carry = 0;
    for (int base = 0; base < NN; base += 1024) {
        int i = base + tid;
        int v = (i < NN) ? deg[i] : 0;
        int x = v;
#pragma unroll
        for (int o = 1; o < 64; o <<= 1) {
            int t = __shfl_up(x, o);
            if (lane >= o) x += t;
        }
        if (lane == 63) wsum[wid] = x;
        __syncthreads();
        if (wid == 0) {
            int w = (lane < 16) ? wsum[lane] : 0;
#pragma unroll
            for (int o = 1; o < 16; o <<= 1) {
                int t = __shfl_up(w, o);
                if (lane >= o) w += t;
            }
            if (lane < 16) wsum[lane] = w;
        }
        __syncthreads();
        int woff = (wid == 0) ? 0 : wsum[wid - 1];
        if (i < NN) row_start[i] = carry + woff + x - v;   // exclusive
        carry += wsum[15];
        __syncthreads();
    }
    if (tid == 0) row_start[NN] = carry;
}

__global__ void fill_kernel(const int* __restrict__ esrc, const int* __restrict__ edst,
                            const int* __restrict__ row_start, int* __restrict__ cursor,
                            int* __restrict__ slot_src) {
    int e = blockIdx.x * 256 + threadIdx.x;
    if (e >= ETOT) return;
    int s, d;
    if (e < EE) { s = esrc[e]; d = edst[e]; }
    else        { s = d = e - EE; }
    int pos = atomicAdd(&cursor[d], 1);
    slot_src[row_start[d] + pos] = s;
}

// ---------------- fp16 MFMA GEMM: C = A[MxK] * Bt[NxK]^T ----------------
// R8 config (best measured): 128x128 tile, 4 waves (2x2), 16x16x32 MFMA, BK=32,
// double-buffered LDS prefetch + explicit producer vmcnt drain, bijective XCD
// swizzle. fp16 operands (fragment/CD layout dtype-independent).
// BIAS_RELU==1: +bias, relu, f32 out. HEADMAJ==1: fp16 head-major planes
// [n/128][M][128].
template<int BIAS_RELU, int HEADMAJ>
__global__ __launch_bounds__(256, 2)
void gemm_f16(const u16* __restrict__ A, const u16* __restrict__ Bt,
              const float* __restrict__ bias, void* __restrict__ Cout,
              int M, int N, int K) {
    __shared__ u16 Als[2][128 * 32];
    __shared__ u16 Bls[2][128 * 32];
    const int tid  = threadIdx.x;
    const int wave = tid >> 6;
    const int lane = tid & 63;

    // bijective XCD swizzle
    const int nwg = gridDim.x * gridDim.y;
    const int bid = blockIdx.y * gridDim.x + blockIdx.x;
    const int q = nwg >> 3, r = nwg & 7;
    const int xcd = bid & 7, idx = bid >> 3;
    const int swz = (xcd < r ? xcd * (q + 1) : r * (q + 1) + (xcd - r) * q) + idx;
    const int bm = (swz / gridDim.x) * 128;
    const int bn = (swz % gridDim.x) * 128;

    const int wr = wave >> 1, wc = wave & 1;   // 2x2 waves, each 64x64
    const int lr = lane & 15;
    const int kc = lane >> 4;

    f32x4 acc[4][4] = {};

    const int srow = tid >> 2;
    const int scol = (tid & 3) * 8;
    int arow0 = bm + srow;       if (arow0 >= M) arow0 = M - 1;
    int arow1 = bm + 64 + srow;  if (arow1 >= M) arow1 = M - 1;
    const int brow0 = bn + srow;
    const int brow1 = bn + 64 + srow;

    const u16* aP0 = A  + (size_t)arow0 * K + scol;
    const u16* aP1 = A  + (size_t)arow1 * K + scol;
    const u16* bP0 = Bt + (size_t)brow0 * K + scol;
    const u16* bP1 = Bt + (size_t)brow1 * K + scol;

    // prologue: stage tile 0 into buf 0
    gld16(aP0, &Als[0][(size_t)wave * 512]);
    gld16(aP1, &Als[0][2048 + (size_t)wave * 512]);
    gld16(bP0, &Bls[0][(size_t)wave * 512]);
    gld16(bP1, &Bls[0][2048 + (size_t)wave * 512]);
    vm_drain();
    __syncthreads();

    int cur = 0;
    for (int k0 = 0; k0 < K; k0 += 32) {
        if (k0 + 32 < K) {
            int nxt = cur ^ 1;
            gld16(aP0 + k0 + 32, &Als[nxt][(size_t)wave * 512]);
            gld16(aP1 + k0 + 32, &Als[nxt][2048 + (size_t)wave * 512]);
            gld16(bP0 + k0 + 32, &Bls[nxt][(size_t)wave * 512]);
            gld16(bP1 + k0 + 32, &Bls[nxt][2048 + (size_t)wave * 512]);
        }

        h16x8 af[4], bg[4];
#pragma unroll
        for (int i = 0; i < 4; ++i)
            af[i] = *(const h16x8*)&Als[cur][(wr * 64 + i * 16 + lr) * 32 + kc * 8];
#pragma unroll
        for (int j = 0; j < 4; ++j)
            bg[j] = *(const h16x8*)&Bls[cur][(wc * 64 + j * 16 + lr) * 32 + kc * 8];
#pragma unroll
        for (int i = 0; i < 4; ++i)
#pragma unroll
            for (int j = 0; j < 4; ++j)
                acc[i][j] = __builtin_amdgcn_mfma_f32_16x16x32_f16(af[i], bg[j], acc[i][j], 0, 0, 0);

        vm_drain();      // prefetch visible to ALL waves before the barrier
        __syncthreads();
        cur ^= 1;
    }

    // C/D layout: col = lane&15, row = (lane>>4)*4 + reg
#pragma unroll
    for (int i = 0; i < 4; ++i) {
#pragma unroll
        for (int r2 = 0; r2 < 4; ++r2) {
            int m = bm + wr * 64 + i * 16 + kc * 4 + r2;
            if (m >= M) continue;
#pragma unroll
            for (int j = 0; j < 4; ++j) {
                int n = bn + wc * 64 + j * 16 + lr;
                float v = acc[i][j][r2];
                if (BIAS_RELU) {
                    v += bias[n];
                    v = fmaxf(v, 0.f);
                    ((float*)Cout)[(size_t)m * N + n] = v;
                } else if (HEADMAJ) {
                    ((u16*)Cout)[(size_t)(n >> 7) * NN * 128 + (size_t)m * 128 + (n & 127)] = f2h(v);
                } else {
                    ((u16*)Cout)[(size_t)m * N + n] = f2h(v);
                }
            }
        }
    }
}

// ---------------- logits: 4 ch/lane vector loads ----------------
// PLANAR: h stored as [head][NN][C] planes. H even: half-wave per head pair member.
template<int H, int C, bool PLANAR>
__global__ __launch_bounds__(128)
void att_logits3(const u16* __restrict__ h, const float* __restrict__ att_s,
                 const float* __restrict__ att_d, float* __restrict__ a_s,
                 float* __restrict__ a_d) {
    const int n = blockIdx.x * 2 + (threadIdx.x >> 6);
    const int lane = threadIdx.x & 63;
    if constexpr (H == 1) {
        const u16* row = h + (size_t)n * C;
        float ps = 0.f, pd = 0.f;
        for (int c = lane * 4; c < C; c += 256) {
            uint2 q = *(const uint2*)(row + c);
            float4 s = *(const float4*)(att_s + c);
            float4 dd = *(const float4*)(att_d + c);
            float v0 = hlo(q.x), v1 = hhi(q.x), v2 = hlo(q.y), v3 = hhi(q.y);
            ps += v0 * s.x + v1 * s.y + v2 * s.z + v3 * s.w;
            pd += v0 * dd.x + v1 * dd.y + v2 * dd.z + v3 * dd.w;
        }
#pragma unroll
        for (int off = 32; off; off >>= 1) {
            ps += __shfl_down(ps, off);
            pd += __shfl_down(pd, off);
        }
        if (lane == 0) { a_s[n] = ps; a_d[n] = pd; }
    } else {
        const int sub = lane >> 5;        // which head of the pair
        const int lg  = lane & 31;        // 32 lanes x 4ch = 128 = C
#pragma unroll
        for (int hp = 0; hp < H / 2; ++hp) {
            const int hd = hp * 2 + sub;
            const int c = lg * 4;
            const u16* rp = PLANAR ? (h + ((size_t)hd * NN + n) * C + c)
                                   : (h + (size_t)n * H * C + hd * C + c);
            uint2 q = *(const uint2*)rp;
            float4 s = *(const float4*)(att_s + hd * C + c);
            float4 dd = *(const float4*)(att_d + hd * C + c);
            float v0 = hlo(q.x), v1 = hhi(q.x), v2 = hlo(q.y), v3 = hhi(q.y);
            float ps = v0 * s.x + v1 * s.y + v2 * s.z + v3 * s.w;
            float pd = v0 * dd.x + v1 * dd.y + v2 * dd.z + v3 * dd.w;
#pragma unroll
            for (int off = 16; off; off >>= 1) {
                ps += __shfl_down(ps, off, 32);
                pd += __shfl_down(pd, off, 32);
            }
            if (lg == 0) {
                a_s[n * H + hd] = ps;
                a_d[n * H + hd] = pd;
            }
        }
    }
}

// ---------------- alpha: unnormalized exp (TRANSPOSED planes [H][ETOT]) + inv sums ----
template<int H>
__global__ __launch_bounds__(128)
void att_alpha3(const int* __restrict__ row_start, const int* __restrict__ slot_src,
                const float* __restrict__ a_s, const float* __restrict__ a_d,
                float* __restrict__ exal_t, float* __restrict__ inv) {
    const int d = blockIdx.x * 2 + (threadIdx.x >> 6);
    const int lane = threadIdx.x & 63;
    const int s0 = row_start[d], s1 = row_start[d + 1];
    float ad[H];
#pragma unroll
    for (int hd = 0; hd < H; ++hd) ad[hd] = a_d[(size_t)d * H + hd];
    float sums[H];
#pragma unroll
    for (int hd = 0; hd < H; ++hd) sums[hd] = 0.f;

    for (int base = s0; base < s1; base += 64) {
        int e = base + lane;
        bool ok = (e < s1);
        int src = ok ? slot_src[e] : 0;
        float as[H];
        if constexpr (H == 1) {
            as[0] = ok ? a_s[src] : 0.f;
        } else {
            const float2* asp = (const float2*)(a_s + (size_t)src * H);
#pragma unroll
            for (int i = 0; i < H / 2; ++i) {
                float2 q = ok ? asp[i] : make_float2(0.f, 0.f);
                as[2 * i] = q.x; as[2 * i + 1] = q.y;
            }
        }
#pragma unroll
        for (int hd = 0; hd < H; ++hd) {
            float t = as[hd] + ad[hd];
            t = (t > 0.f) ? t : 0.2f * t;          // leaky_relu 0.2
            float x = ok ? expf(t) : 0.f;          // logits small by construction
            sums[hd] += x;
            if (ok) exal_t[(size_t)hd * ETOT + e] = x;   // coalesced per plane
        }
    }
#pragma unroll
    for (int hd = 0; hd < H; ++hd) {
#pragma unroll
        for (int off = 32; off; off >>= 1) sums[hd] += __shfl_down(sums[hd], off);
    }
    if (lane == 0) {
#pragma unroll
        for (int hd = 0; hd < H; ++hd) inv[(size_t)d * H + hd] = 1.f / (sums[hd] + 1e-16f);
    }
}

// helper: accumulate 8 fp16 channels from a uint4 (scalar fallback)
__device__ __forceinline__ void fma8h(float* acc, uint4 g, float a) {
    acc[0] += a * hlo(g.x); acc[1] += a * hhi(g.x);
    acc[2] += a * hlo(g.y); acc[3] += a * hhi(g.y);
    acc[4] += a * hlo(g.z); acc[5] += a * hhi(g.z);
    acc[6] += a * hlo(g.w); acc[7] += a * hhi(g.w);
}

#ifdef USE_FDOT2
// paired-edge accumulate: acc[c] += aA*hA[c] + aB*hB[c] via v_perm + v_dot2_f32_f16
__device__ __forceinline__ void dot8h(float* acc, uint4 gA, uint4 gB, h16x2 ap) {
    u32 p;
    p = __builtin_amdgcn_perm(gB.x, gA.x, 0x05040100u);
    acc[0] = __builtin_amdgcn_fdot2(as_h2(p), ap, acc[0], false);
    p = __builtin_amdgcn_perm(gB.x, gA.x, 0x07060302u);
    acc[1] = __builtin_amdgcn_fdot2(as_h2(p), ap, acc[1], false);
    p = __builtin_amdgcn_perm(gB.y, gA.y, 0x05040100u);
    acc[2] = __builtin_amdgcn_fdot2(as_h2(p), ap, acc[2], false);
    p = __builtin_amdgcn_perm(gB.y, gA.y, 0x07060302u);
    acc[3] = __builtin_amdgcn_fdot2(as_h2(p), ap, acc[3], false);
    p = __builtin_amdgcn_perm(gB.z, gA.z, 0x05040100u);
    acc[4] = __builtin_amdgcn_fdot2(as_h2(p), ap, acc[4], false);
    p = __builtin_amdgcn_perm(gB.z, gA.z, 0x07060302u);
    acc[5] = __builtin_amdgcn_fdot2(as_h2(p), ap, acc[5], false);
    p = __builtin_amdgcn_perm(gB.w, gA.w, 0x05040100u);
    acc[6] = __builtin_amdgcn_fdot2(as_h2(p), ap, acc[6], false);
    p = __builtin_amdgcn_perm(gB.w, gA.w, 0x07060302u);
    acc[7] = __builtin_amdgcn_fdot2(as_h2(p), ap, acc[7], false);
}
#endif

// shared gather-accumulate body: one 16-lane group, one dst, 128 channels
template<int ACT>
__device__ __forceinline__ void scatter_body(
        int d, int cc, const int* __restrict__ row_start,
        const int* __restrict__ slot_src, const float* __restrict__ exp_pl,
        float sc_inv_sel, const u16* hb, int hstride,
        const float* __restrict__ bias, u16* __restrict__ out, int HC, int lg) {
    const int s0 = row_start[d], s1 = row_start[d + 1];
    float acc0[8] = {}, acc1[8] = {};
    for (int base = s0; base < s1; base += 16) {
        int e = base + lg;
        bool ok = (e < s1);
        int mySrc = 0; float mA = 0.f;
        if (ok) { mySrc = slot_src[e]; mA = exp_pl[e]; }
        int cnt = min(16, s1 - base);
        int j = 0;
#ifdef USE_FDOT2
        for (; j + 4 <= cnt; j += 4) {
            int sA = __shfl(mySrc, j, 16),     sB = __shfl(mySrc, j + 1, 16);
            int sC = __shfl(mySrc, j + 2, 16), sD = __shfl(mySrc, j + 3, 16);
            float aA = __shfl(mA, j, 16),     aB = __shfl(mA, j + 1, 16);
            float aC = __shfl(mA, j + 2, 16), aD = __shfl(mA, j + 3, 16);
            h16x2 apAB = pk2h(aA, aB);
            h16x2 apCD = pk2h(aC, aD);
            uint4 gA = *(const uint4*)(hb + (size_t)sA * hstride);
            uint4 gB = *(const uint4*)(hb + (size_t)sB * hstride);
            uint4 gC = *(const uint4*)(hb + (size_t)sC * hstride);
            uint4 gD = *(const uint4*)(hb + (size_t)sD * hstride);
            dot8h(acc0, gA, gB, apAB);
            dot8h(acc1, gC, gD, apCD);
        }
        for (; j < cnt; ++j) {
            int sA = __shfl(mySrc, j, 16);
            float aA = __shfl(mA, j, 16);
            uint4 gA = *(const uint4*)(hb + (size_t)sA * hstride);
            fma8h(acc0, gA, aA);
        }
#else
        for (; j + 2 <= cnt; j += 2) {
            int sA = __shfl(mySrc, j, 16),     sB = __shfl(mySrc, j + 1, 16);
            float aA = __shfl(mA, j, 16),     aB = __shfl(mA, j + 1, 16);
            uint4 gA = *(const uint4*)(hb + (size_t)sA * hstride);
            uint4 gB = *(const uint4*)(hb + (size_t)sB * hstride);
            fma8h(acc0, gA, aA);
            fma8h(acc1, gB, aB);
        }
        for (; j < cnt; ++j) {
            int sA = __shfl(mySrc, j, 16);
            float aA = __shfl(mA, j, 16);
            uint4 gA = *(const uint4*)(hb + (size_t)sA * hstride);
            fma8h(acc0, gA, aA);
        }
#endif
    }
    float4 b0 = *(const float4*)(bias + cc);
    float4 b1 = *(const float4*)(bias + cc + 4);
    float bb[8] = { b0.x, b0.y, b0.z, b0.w, b1.x, b1.y, b1.z, b1.w };
    u16 os[8];
#pragma unroll
    for (int k = 0; k < 8; ++k) {
        float v = acc0[k] + acc1[k];
        v = v * sc_inv_sel + bb[k];
        if (ACT == 1) v = (v > 0.f) ? v : (expf(v) - 1.f);   // elu
        else          v = fmaxf(v, 0.f);                      // relu
        os[k] = f2h(v);
    }
    uint4 qo;
    qo.x = (u32)os[0] | ((u32)os[1] << 16);
    qo.y = (u32)os[2] | ((u32)os[3] << 16);
    qo.z = (u32)os[4] | ((u32)os[5] << 16);
    qo.w = (u32)os[6] | ((u32)os[7] << 16);
    *(uint4*)(out + (size_t)d * HC + cc) = qo;
}

// ---------------- scatter x1 (layer 1): XCD-affine planar ----------------
__global__ __launch_bounds__(128)
void gat_scatter_x1(const int* __restrict__ row_start, const int* __restrict__ slot_src,
                    const float* __restrict__ exal_t, const float* __restrict__ inv,
                    const u16* __restrict__ h, const float* __restrict__ bias,
                    u16* __restrict__ out) {
    const int bid = blockIdx.x;
    const int k = bid & 7;
    const int t = bid >> 3;
    const int uidx = t / 625;
    const int loc  = t - uidx * 625;
    const int unit = k + 8 * uidx;
    if (unit >= 2 * H1) return;
    const int plane = unit >> 1;
    const int half  = unit & 1;
    const int grp = threadIdx.x >> 4;
    const int lg  = threadIdx.x & 15;
    const int d  = half * (NN / 2) + loc * 8 + grp;
    const int cc = plane * 128 + lg * 8;
    const float* exp_pl = exal_t + (size_t)plane * ETOT;
    const u16* hb = h + (size_t)plane * NN * 128 + lg * 8;
    scatter_body<1>(d, cc, row_start, slot_src, exp_pl,
                    inv[(size_t)d * H1 + plane], hb, 128, bias, out, HC1, lg);
}

// ---------------- scatter x2 (layer 2): XCD-affine channel slices ----------------
__global__ __launch_bounds__(128)
void gat_scatter_x2(const int* __restrict__ row_start, const int* __restrict__ slot_src,
                    const float* __restrict__ exal_t, const float* __restrict__ inv,
                    const u16* __restrict__ h, const float* __restrict__ bias,
                    u16* __restrict__ out) {
    const int bid = blockIdx.x;
    const int slice = bid & 7;
    const int chunk = bid >> 3;
    const int grp = threadIdx.x >> 4;
    const int lg  = threadIdx.x & 15;
    const int d  = chunk * 8 + grp;
    const int cc = slice * 128 + lg * 8;
    const u16* hb = h + cc;
    scatter_body<2>(d, cc, row_start, slot_src, exal_t,
                    inv[d], hb, HC2, bias, out, HC2, lg);
}

extern "C" void kernel_launch(void* const* d_in, const int* in_sizes, int n_in,
                              void* d_out, int out_size, void* d_ws, size_t ws_size,
                              hipStream_t stream) {
    const float* node      = (const float*)d_in[0];
    const int*   esrc      = (const int*)d_in[1];          // edge_index[0]
    const int*   edst      = ((const int*)d_in[1]) + EE;   // edge_index[1]
    const float* W1        = (const float*)d_in[2];
    const float* att_src1  = (const float*)d_in[3];
    const float* att_dst1  = (const float*)d_in[4];
    const float* b1        = (const float*)d_in[5];
    const float* W2        = (const float*)d_in[6];
    const float* att_src2  = (const float*)d_in[7];
    const float* att_dst2  = (const float*)d_in[8];
    const float* b2        = (const float*)d_in[9];
    const float* fc_w      = (const float*)d_in[10];
    const float* fc_b      = (const float*)d_in[11];
    float* out = (float*)d_out;

    // ---- workspace layout ----
    u16* bufA  = (u16*)d_ws;                        // [NN*HC1]  h1 planes, later h2
    u16* bufB  = bufA + (size_t)NN * HC1;           // [NN*HC1]  x2, later out2
    u16* nodeb = bufB + (size_t)NN * HC1;           // [NN*F_IN]
    u16* w1t   = nodeb + (size_t)NN * F_IN;         // [HC1*F_IN]
    u16* w2t   = w1t + (size_t)HC1 * F_IN;          // [HC2*HC1]
    u16* fcwt  = w2t + (size_t)HC2 * HC1;           // [OUT_DIM*OUT_DIM]
    float* exal  = (float*)(fcwt + (size_t)OUT_DIM * OUT_DIM);  // [H1*ETOT] planes
    float* inv   = exal + (size_t)ETOT * H1;        // [NN*H1]
    float* a_s1  = inv + (size_t)NN * H1;           // [NN*H1]
    float* a_d1  = a_s1 + (size_t)NN * H1;
    float* a_s2  = a_d1 + (size_t)NN * H1;          // [NN]
    float* a_d2  = a_s2 + NN;
    int* deg       = (int*)(a_d2 + NN);
    int* cursor    = deg + NN;
    int* row_start = cursor + NN;                   // [NN+1]
    int* slot_src  = row_start + NN + 8;            // [ETOT]

    // ---- fused prep (conversions + transposes + histogram) ----
    hipMemsetAsync(deg, 0, 2 * NN * sizeof(int), stream);  // deg + cursor
    prep_kernel<<<PREP_BLKS, 256, 0, stream>>>(node, nodeb, W1, w1t, W2, w2t,
                                               fc_w, fcwt, edst, deg);
    scan_kernel<<<1, 1024, 0, stream>>>(deg, row_start);
    fill_kernel<<<(ETOT + 255) / 256, 256, 0, stream>>>(esrc, edst, row_start, cursor, slot_src);

    // ---- layer 1 (h1 stored as head-major planes) ----
    gemm_f16<0, 1><<<dim3(HC1 / 128, (NN + 127) / 128), 256, 0, stream>>>(nodeb, w1t, nullptr, bufA, NN, HC1, F_IN);
    att_logits3<H1, C1, true><<<NN / 2, 128, 0, stream>>>(bufA, att_src1, att_dst1, a_s1, a_d1);
    att_alpha3<H1><<<NN / 2, 128, 0, stream>>>(row_start, slot_src, a_s1, a_d1, exal, inv);
    gat_scatter_x1<<<15000, 128, 0, stream>>>(row_start, slot_src, exal, inv, bufA, b1, bufB);

    // ---- layer 2 (node-major, XCD-affine channel slices) ----
    gemm_f16<0, 0><<<dim3(HC2 / 128, (NN + 127) / 128), 256, 0, stream>>>(bufB, w2t, nullptr, bufA, NN, HC2, HC1);
    att_logits3<H2, C2, false><<<NN / 2, 128, 0, stream>>>(bufA, att_src2, att_dst2, a_s2, a_d2);
    att_alpha3<H2><<<NN / 2, 128, 0, stream>>>(row_start, slot_src, a_s2, a_d2, exal, inv);
    gat_scatter_x2<<<10000, 128, 0, stream>>>(row_start, slot_src, exal, inv, bufA, b2, bufB);

    // ---- fc: out = relu(out2 @ fc_w + fc_b), f32 out ----
    gemm_f16<1, 0><<<dim3(OUT_DIM / 128, (NN + 127) / 128), 256, 0, stream>>>(bufB, fcwt, fc_b, out, NN, OUT_DIM, OUT_DIM);
}